// Round 11
// baseline (1021.977 us; speedup 1.0000x reference)
//
#include <hip/hip_runtime.h>
#include <hip/hip_bf16.h>
#include <hip/hip_fp16.h>

// CellTrack GNN, MI355X — R24: persistent k_edge_mlp + cross-tile gather prefetch.
// R23 (851us, best): k_edge_mlp 378us; phases serialize (gather exposed at
// kernel start). Register pipelining failed at instruction level (R16 sink /
// R17 MFMA hoist), but __syncthreads() is a fence the compiler MUST respect
// for memory ops on both sides. R24: grid 512 persistent blocks (2/CU), each
// loops ~15 tiles; tile i+1's gather loads issue after GEMM3 of tile i
// (consumers after the loop-end barrier -> loads cannot sink, consumers
// cannot hoist). ~40 VGPR prefetch state is the proof-signal (56 -> ~100).
// ws: AGG|EB|WT|XH|XNH|X1P|X2H|BF|CNT|POS|TEX|ES|ET|OID|BS|BSSE ~201MB.

using fp16 = __half;
typedef _Float16 h16;
typedef _Float16 f16x8 __attribute__((ext_vector_type(8)));
typedef _Float16 h16x2 __attribute__((ext_vector_type(2)));
typedef short s16x8 __attribute__((ext_vector_type(8)));
typedef float f32x4 __attribute__((ext_vector_type(4)));

#define NN 50000
#define EE 500000
#define EPSC 1e-8f
#define SCAN_B 196   // ceil(NN/256)
#define NTILES 7813  // ceil(EE/64)
#define PGRID 512    // persistent blocks (2/CU x 256 CU)

__device__ __forceinline__ float reluf(float v){ return v > 0.f ? v : 0.f; }

__device__ __forceinline__ float dot8(const f16x8 a, const f16x8 b, float acc)
{
#pragma unroll
  for (int i = 0; i < 4; ++i) {
    const h16x2 av = {a[2 * i], a[2 * i + 1]};
    const h16x2 bv = {b[2 * i], b[2 * i + 1]};
    acc = __builtin_amdgcn_fdot2(av, bv, acc, false);
  }
  return acc;
}

__device__ __forceinline__ f16x8 absdiff8(const f16x8 a, const f16x8 b)
{
  const f16x8 d = a - b;
  s16x8 di = __builtin_bit_cast(s16x8, d);
  di &= (short)0x7fff;
  return __builtin_bit_cast(f16x8, di);
}

// WT sub-buffer offsets (halves)
#define OFF_E1   0         // [256][544]  (527 real, permuted col order)
#define OFF_E2   139264    // [128][256]
#define OFF_MSG  172032    // [128][256]  ([e|xs] order)
#define OFF_NODE 204800    // [128][256]
#define OFF_MP1  237568    // [256][384]
#define OFF_MP2  335872    // [128][256]
#define OFF_C1   368640    // [64][128]
#define OFF_N1   376832    // [512][160]  block-diag [Wh1 | Wl1]
#define OFF_N2   458752    // [128][512]  block-diag [Wh2 ; Wl2]
#define WT_TOTAL 524288
#define BF_TOTAL 640

// ---------------------------------------------------------------------------
__global__ __launch_bounds__(256) void k_prep(
    const float* __restrict__ We1, const float* __restrict__ We2,
    const float* __restrict__ Wmsg, const float* __restrict__ Wnode,
    const float* __restrict__ Wmp1, const float* __restrict__ Wmp2,
    const float* __restrict__ Wc1,
    const float* __restrict__ Wh1, const float* __restrict__ Wl1,
    const float* __restrict__ Wh2, const float* __restrict__ Wl2,
    const float* __restrict__ bh1, const float* __restrict__ bl1,
    const float* __restrict__ bh2, const float* __restrict__ bl2,
    h16* __restrict__ WT, float* __restrict__ BF)
{
  int idx = blockIdx.x * 256 + threadIdx.x;
  if (idx >= WT_TOTAL) {
    const int b = idx - WT_TOTAL;
    if (b < 512) BF[b] = (b < 256) ? bh1[b] : bl1[b - 256];
    else if (b < BF_TOTAL) {
      const int c = b - 512;
      BF[b] = (c < 32) ? bh2[c] : bl2[c - 32];
    }
    return;
  }
  h16 v;
  if (idx < OFF_E2) {
    const int L = idx, n = L / 544, k = L % 544;
    int r;
    if      (k < 128) r = 142 + k;
    else if (k < 256) r = 270 + (k - 128);
    else if (k < 384) r = 398 + (k - 256);
    else if (k < 512) r = 13 + (k - 384);
    else if (k < 525) r = k - 512;
    else if (k == 528) r = 141;
    else if (k == 529) r = 526;
    else r = -1;
    v = (h16)((r >= 0) ? We1[r * 256 + n] : 0.f);
  } else if (idx < OFF_MSG) {
    const int L = idx - OFF_E2, n = L >> 8, k = L & 255;
    v = (h16)We2[k * 128 + n];
  } else if (idx < OFF_NODE) {
    const int L = idx - OFF_MSG, n = L >> 8, k = L & 255;
    const int ko = (k < 128) ? (128 + k) : (k - 128);   // [e|xs] order
    v = (h16)Wmsg[ko * 128 + n];
  } else if (idx < OFF_MP1) {
    const int L = idx - OFF_NODE, n = L >> 8, k = L & 255;
    v = (h16)Wnode[k * 128 + n];
  } else if (idx < OFF_MP2) {
    const int L = idx - OFF_MP1, n = L / 384, k = L % 384;
    v = (h16)Wmp1[k * 256 + n];
  } else if (idx < OFF_C1) {
    const int L = idx - OFF_MP2, n = L >> 8, k = L & 255;
    v = (h16)Wmp2[k * 128 + n];
  } else if (idx < OFF_N1) {
    const int L = idx - OFF_C1, n = L >> 7, k = L & 127;
    v = (h16)Wc1[k * 64 + n];
  } else if (idx < OFF_N2) {
    const int L = idx - OFF_N1, n = L / 160, k = L % 160;
    float f = 0.f;
    if (n < 256) { if (k < 13) f = Wh1[k * 256 + n]; }
    else { if (k >= 16 && k < 144) f = Wl1[(k - 16) * 256 + (n - 256)]; }
    v = (h16)f;
  } else {
    const int L = idx - OFF_N2, n = L >> 9, k = L & 511;
    float f = 0.f;
    if (n < 32) { if (k < 256) f = Wh2[k * 32 + n]; }
    else { if (k >= 256) f = Wl2[(k - 256) * 96 + (n - 32)]; }
    v = (h16)f;
  }
  WT[idx] = v;
}

// k_cvt: x1 -> fp16 mirror padded to 16/row, x2 -> fp16; + trg histogram.
__global__ __launch_bounds__(256) void k_cvt(
    const float* __restrict__ x1, const float* __restrict__ x2,
    const int* __restrict__ ei,
    h16* __restrict__ X1P, h16* __restrict__ X2H, int* __restrict__ CNT)
{
  const int idx = blockIdx.x * 256 + threadIdx.x;
  if (idx < EE) atomicAdd(&CNT[ei[EE + idx]], 1);
  if (idx < NN * 16) {
    const int nn = idx >> 4, j = idx & 15;
    X1P[idx] = (h16)((j < 13) ? x1[nn * 13 + j] : 0.f);
  }
  const int i2 = idx - NN * 16;
  if (i2 >= 0 && i2 < NN * 128) X2H[i2] = (h16)x2[i2];
}

// --------------------------- hierarchical scan -----------------------------
__global__ __launch_bounds__(256) void k_scanA(
    const int* __restrict__ CNT, int* __restrict__ TEX, int* __restrict__ BS)
{
  __shared__ int sd[256];
  const int tid = threadIdx.x;
  const int i = blockIdx.x * 256 + tid;
  const int v = (i < NN) ? CNT[i] : 0;
  sd[tid] = v;
  __syncthreads();
  for (int off = 1; off < 256; off <<= 1) {
    const int x = (tid >= off) ? sd[tid - off] : 0;
    __syncthreads();
    sd[tid] += x;
    __syncthreads();
  }
  if (i < NN) TEX[i] = sd[tid] - v;
  if (tid == 255) BS[blockIdx.x] = sd[255];
}

__global__ __launch_bounds__(256) void k_scanB(
    const int* __restrict__ BS, int* __restrict__ BSSE)
{
  __shared__ int sd[256];
  const int tid = threadIdx.x;
  const int v = (tid < SCAN_B) ? BS[tid] : 0;
  sd[tid] = v;
  __syncthreads();
  for (int off = 1; off < 256; off <<= 1) {
    const int x = (tid >= off) ? sd[tid - off] : 0;
    __syncthreads();
    sd[tid] += x;
    __syncthreads();
  }
  if (tid < SCAN_B) BSSE[tid] = sd[tid] - v;
}

__global__ __launch_bounds__(256) void k_scatter(
    const int* __restrict__ ei, const int* __restrict__ TEX,
    const int* __restrict__ BSSE, int* __restrict__ POS,
    int* __restrict__ ES, int* __restrict__ ET, int* __restrict__ OID)
{
  const int e = blockIdx.x * 256 + threadIdx.x;
  if (e >= EE) return;
  const int t = ei[EE + e];
  const int p = atomicAdd(&POS[t], 1);
  const int idx = BSSE[t >> 8] + TEX[t] + p;
  ES[idx] = ei[e];
  ET[idx] = t;
  OID[idx] = e;
}

// ---------------------------------------------------------------------------
// MFMA GEMM: C[ROWS][UDIM] = act(A[ROWS][KP] @ WT^T + b). RS=1 everywhere.
// ---------------------------------------------------------------------------
template<int ROWS, int UDIM, int KP, int LDA, int WAVES, int RS, bool RELU,
         bool ENDSYNC, typename F>
__device__ __forceinline__ void mfma_gemm(const h16* sA,
    const h16* __restrict__ WT, const float* __restrict__ bias, F emit)
{
  constexpr int CS = WAVES / RS;
  constexpr int RG = ROWS / RS;
  constexpr int RT = RG / 16;
  constexpr int NPW0 = UDIM / CS;
  constexpr int NPW = (NPW0 < 16) ? 16 : NPW0;
  constexpr int NT = NPW / 16;
  constexpr int NSTEPS = KP / 32;
  constexpr int CH0 = (NT >= 8) ? 1 : ((NT >= 4) ? 2 : 4);
  constexpr int CHUNK = (NSTEPS < CH0) ? NSTEPS : CH0;
  constexpr int NCH = (NSTEPS + CHUNK - 1) / CHUNK;
  const int tid = threadIdx.x;
  const int wave = tid >> 6;
  const int lane = tid & 63;
  const int m = lane & 15;
  const int quad = lane >> 4;
  const int wr = wave % RS;
  const int wc = wave / RS;
  const int rbase = wr * RG;
  const int n0 = wc * NPW;
  const bool active = (n0 < UDIM);

  f32x4 acc[RT][NT];
#pragma unroll
  for (int r = 0; r < RT; ++r)
#pragma unroll
    for (int j = 0; j < NT; ++j) acc[r][j] = (f32x4){0.f, 0.f, 0.f, 0.f};
  float bb[NT];

  if (active) {
    const h16* wbase = &WT[(size_t)(n0 + m) * KP + quad * 8];
#pragma unroll
    for (int j = 0; j < NT; ++j) bb[j] = bias[n0 + j * 16 + m];

    f16x8 breg[2][CHUNK][NT];
#pragma unroll
    for (int s = 0; s < CHUNK; ++s)
      if (s < NSTEPS)
#pragma unroll
        for (int j = 0; j < NT; ++j)
          breg[0][s][j] = *(const f16x8*)&wbase[(size_t)j * 16 * KP + s * 32];
    asm volatile("" ::: "memory");

#pragma unroll
    for (int c = 0; c < NCH; ++c) {
      if (c + 1 < NCH) {
#pragma unroll
        for (int s = 0; s < CHUNK; ++s) {
          const int st = (c + 1) * CHUNK + s;
          if (st < NSTEPS)
#pragma unroll
            for (int j = 0; j < NT; ++j)
              breg[(c + 1) & 1][s][j] =
                  *(const f16x8*)&wbase[(size_t)j * 16 * KP + st * 32];
        }
      }
#pragma unroll
      for (int s = 0; s < CHUNK; ++s) {
        const int st = c * CHUNK + s;
        if (st < NSTEPS) {
          const int k0 = st * 32;
#pragma unroll
          for (int r = 0; r < RT; ++r) {
            const f16x8 af = *(const f16x8*)&sA[(rbase + r * 16 + m) * LDA + k0 + quad * 8];
#pragma unroll
            for (int j = 0; j < NT; ++j)
              acc[r][j] = __builtin_amdgcn_mfma_f32_16x16x32_f16(af, breg[c & 1][s][j], acc[r][j], 0, 0, 0);
          }
        }
      }
      asm volatile("" ::: "memory");
    }
  }
  __syncthreads();
  if (active) {
#pragma unroll
    for (int j = 0; j < NT; ++j) {
      const int col = n0 + j * 16 + m;
#pragma unroll
      for (int r = 0; r < RT; ++r)
#pragma unroll
        for (int g = 0; g < 4; ++g) {
          const int row = rbase + r * 16 + quad * 4 + g;
          float v = acc[r][j][g] + bb[j];
          if (RELU) v = reluf(v);
          emit(row, col, v);
        }
    }
  }
  if (ENDSYNC) __syncthreads();
}

// ---------------------------------------------------------------------------
// K0: node encoder via MFMA. 32 nodes/block, 512 thr (grid 1563, last 16).
// ---------------------------------------------------------------------------
__global__ __launch_bounds__(512, 4) void k_nenc(
    const h16* __restrict__ X1P, const h16* __restrict__ X2H,
    const h16* __restrict__ WT, const float* __restrict__ BF,
    h16* __restrict__ XH)
{
  __shared__ __align__(16) h16 sA[32 * 168];
  __shared__ __align__(16) h16 sH[32 * 520];
  const int tid = threadIdx.x;
  const int n0 = blockIdx.x * 32;
  const int remn = NN - n0;
  const int cnt = remn < 32 ? remn : 32;
  const int n = tid >> 4;
  const int q = tid & 15;

  if (n < cnt) {
    const int node = n0 + n;
    if (q < 2)
      *(f16x8*)&sA[n * 168 + q * 8] = *(const f16x8*)&X1P[node * 16 + q * 8];
    else if (q < 4)
      *(f16x8*)&sA[n * 168 + 144 + (q - 2) * 8] = (f16x8){};
    *(f16x8*)&sA[n * 168 + 16 + q * 8] =
        *(const f16x8*)&X2H[(size_t)node * 128 + q * 8];
  }
  __syncthreads();

  mfma_gemm<32, 512, 160, 168, 8, 1, true, true>(sA, WT + OFF_N1, BF,
      [&](int row, int col, float v) { sH[row * 520 + col] = (h16)v; });
  mfma_gemm<32, 128, 512, 520, 8, 1, false, false>(sH, WT + OFF_N2, BF + 512,
      [&](int row, int col, float v) {
        if (row < cnt) XH[(size_t)(n0 + row) * 128 + col] = (h16)v;
      });
}

// ---------------------------------------------------------------------------
// K2: PERSISTENT fused edge kernel. Grid 512 (2 blk/CU), each block loops
// tiles bid, bid+512, ... Cross-tile gather prefetch: tile i+1's loads issue
// after GEMM3 of tile i; consumers (VALU + ds_write) sit after the loop-end
// __syncthreads -> compiler cannot sink loads / hoist consumers across it.
// ---------------------------------------------------------------------------
__global__ __launch_bounds__(512, 4) void k_edge_mlp(
    const h16* __restrict__ X1P, const h16* __restrict__ X2H,
    const int* __restrict__ ES, const int* __restrict__ ET,
    const h16* __restrict__ XH, const h16* __restrict__ WT,
    const float* __restrict__ be1, const float* __restrict__ be2,
    const float* __restrict__ bmsg,
    h16* __restrict__ EB, float* __restrict__ AGG)
{
  __shared__ __align__(16) h16 sFeat[64 * 568];
  __shared__ int strg[64];
  const int tid = threadIdx.x;
  const int n = tid >> 3;
  const int q = tid & 7;
  h16* Arow = &sFeat[n * 568];

  // prefetch state (~40 VGPR): lives across the GEMMs of the previous tile
  int pt = 0;
  f16x8 p1a = {}, p1b = {};
  f16x8 p2a0 = {}, p2a1 = {}, p2b0 = {}, p2b1 = {};
  f16x8 pha0 = {}, pha1 = {}, phb0 = {}, phb1 = {};

  auto issue = [&](long tl) {
    const long e0 = tl * 64;
    const long rem = (long)EE - e0;
    const int cnt = rem < 64 ? (int)rem : 64;
    int s = 0, t = 0;
    if (n < cnt) { s = ES[e0 + n]; t = ET[e0 + n]; }
    pt = t;
    if (q < 2) {
      p1a = *(const f16x8*)&X1P[s * 16 + q * 8];
      p1b = *(const f16x8*)&X1P[t * 16 + q * 8];
    }
    p2a0 = *(const f16x8*)&X2H[(size_t)s * 128 + q * 16];
    p2a1 = *(const f16x8*)&X2H[(size_t)s * 128 + q * 16 + 8];
    p2b0 = *(const f16x8*)&X2H[(size_t)t * 128 + q * 16];
    p2b1 = *(const f16x8*)&X2H[(size_t)t * 128 + q * 16 + 8];
    pha0 = *(const f16x8*)&XH[(size_t)s * 128 + q * 16];
    pha1 = *(const f16x8*)&XH[(size_t)s * 128 + q * 16 + 8];
    phb0 = *(const f16x8*)&XH[(size_t)t * 128 + q * 16];
    phb1 = *(const f16x8*)&XH[(size_t)t * 128 + q * 16 + 8];
  };

  long tile = blockIdx.x;
  issue(tile);   // prologue gather (PGRID < NTILES always)

  for (; tile < NTILES; tile += PGRID) {
    const long e0 = tile * 64;
    const long rem = (long)EE - e0;
    const int cnt = rem < 64 ? (int)rem : 64;

    // ---- feature compute from prefetched regs -> sFeat / strg ----
    if (n < cnt) {
      if (q == 0) strg[n] = pt;
      float ds = 0.f, ns = 0.f, nt = 0.f;
      if (q < 2) {
        ds = dot8(p1a, p1b, ds); ns = dot8(p1a, p1a, ns); nt = dot8(p1b, p1b, nt);
        *(f16x8*)&Arow[512 + q * 8] = absdiff8(p1a, p1b);
      }
      ds = dot8(p2a0, p2b0, ds); ns = dot8(p2a0, p2a0, ns); nt = dot8(p2b0, p2b0, nt);
      *(f16x8*)&Arow[384 + q * 16] = absdiff8(p2a0, p2b0);
      ds = dot8(p2a1, p2b1, ds); ns = dot8(p2a1, p2a1, ns); nt = dot8(p2b1, p2b1, nt);
      *(f16x8*)&Arow[384 + q * 16 + 8] = absdiff8(p2a1, p2b1);
      ds += __shfl_xor(ds, 1); ds += __shfl_xor(ds, 2); ds += __shfl_xor(ds, 4);
      ns += __shfl_xor(ns, 1); ns += __shfl_xor(ns, 2); ns += __shfl_xor(ns, 4);
      nt += __shfl_xor(nt, 1); nt += __shfl_xor(nt, 2); nt += __shfl_xor(nt, 4);
      if (q == 0)
        Arow[528] = (h16)(ds / (fmaxf(sqrtf(ns), EPSC) * fmaxf(sqrtf(nt), EPSC)));

      float ds2 = 0.f, ns2 = 0.f, nt2 = 0.f;
      ds2 = dot8(pha0, phb0, ds2); ns2 = dot8(pha0, pha0, ns2); nt2 = dot8(phb0, phb0, nt2);
      *(f16x8*)&Arow[q * 16]       = pha0;
      *(f16x8*)&Arow[128 + q * 16] = phb0;
      *(f16x8*)&Arow[256 + q * 16] = absdiff8(pha0, phb0);
      ds2 = dot8(pha1, phb1, ds2); ns2 = dot8(pha1, pha1, ns2); nt2 = dot8(phb1, phb1, nt2);
      *(f16x8*)&Arow[q * 16 + 8]       = pha1;
      *(f16x8*)&Arow[128 + q * 16 + 8] = phb1;
      *(f16x8*)&Arow[256 + q * 16 + 8] = absdiff8(pha1, phb1);
      ds2 += __shfl_xor(ds2, 1); ds2 += __shfl_xor(ds2, 2); ds2 += __shfl_xor(ds2, 4);
      ns2 += __shfl_xor(ns2, 1); ns2 += __shfl_xor(ns2, 2); ns2 += __shfl_xor(ns2, 4);
      nt2 += __shfl_xor(nt2, 1); nt2 += __shfl_xor(nt2, 2); nt2 += __shfl_xor(nt2, 4);
      if (q == 0)
        Arow[529] = (h16)(ds2 / (fmaxf(sqrtf(ns2), EPSC) * fmaxf(sqrtf(nt2), EPSC)));
      for (int j = 530 + q; j < 544; j += 8) Arow[j] = (h16)0.f;
    } else {
      if (q == 0) strg[n] = 0;
      for (int j8 = q; j8 < 71; j8 += 8) *(f16x8*)&Arow[j8 * 8] = (f16x8){};
    }
    __syncthreads();

    h16* sHid = sFeat;   // stride 264, overlays features (post-barrier)
    mfma_gemm<64, 256, 544, 568, 8, 1, true, true>(sFeat, WT + OFF_E1, be1,
        [&](int row, int col, float v) { sHid[row * 264 + col] = (h16)v; });
    mfma_gemm<64, 128, 256, 264, 8, 1, false, false>(sHid, WT + OFF_E2, be2,
        [&](int row, int col, float v) {
          const h16 vh = (h16)v;
          if (row < cnt) EB[(size_t)(e0 + row) * 128 + col] = vh;
          sHid[row * 264 + col] = vh;              // e at cols [0,128)
        });
    // park xs (current tile's pha0/pha1 — read BEFORE issue() overwrites)
    *(f16x8*)&sFeat[n * 264 + 128 + q * 16]     = pha0;
    *(f16x8*)&sFeat[n * 264 + 128 + q * 16 + 8] = pha1;
    __syncthreads();
    // msg GEMM: emit fp32 into the (dead, post-barrier) A region, stride 528B
    mfma_gemm<64, 128, 256, 264, 8, 1, true, true>(sFeat, WT + OFF_MSG, bmsg,
        [&](int row, int col, float v) {
          *(float*)((char*)sFeat + row * 528 + col * 4) = v;
        });
    // ---- prefetch next tile: loads issue here, consumers after loop barrier
    if (tile + PGRID < NTILES) issue(tile + PGRID);
    // ---- segment reduction: sorted trg -> runs; 4 row-groups x 128 cols
    {
      const int c = tid & 127;
      const int g = tid >> 7;
      const int r0 = g * 16;
      if (r0 < cnt) {
        const int rend = (r0 + 16 < cnt) ? r0 + 16 : cnt;
        float acc = 0.f;
        int cur = strg[r0];
        for (int r = r0; r < rend; ++r) {
          const int t = strg[r];
          if (t != cur) {
            atomicAdd(&AGG[(size_t)cur * 128 + c], acc);
            acc = 0.f; cur = t;
          }
          acc += *(const float*)((const char*)sFeat + r * 528 + c * 4);
        }
        atomicAdd(&AGG[(size_t)cur * 128 + c], acc);
      }
    }
    __syncthreads();   // protects sFeat/strg reuse; fences the prefetch
  }
}

// ---------------------------------------------------------------------------
// K3: xn = relu([x|agg] @ Wnode + b). 64 nodes/block.
// ---------------------------------------------------------------------------
__global__ __launch_bounds__(256, 4) void k_node_update(
    const h16* __restrict__ XH, const float* __restrict__ AGG,
    const h16* __restrict__ WT, const float* __restrict__ bnode,
    h16* __restrict__ XNH)
{
  __shared__ __align__(16) h16 sA[64 * 264];
  const int tid = threadIdx.x;
  const int n0 = blockIdx.x * 64;
  const int remn = NN - n0;
  const int cnt = remn < 64 ? remn : 64;
  const int n = tid >> 2;
  const int q = tid & 3;

  if (n < cnt) {
    const f16x8* xr = (const f16x8*)&XH[(size_t)(n0 + n) * 128];
    const float4* ar = (const float4*)&AGG[(size_t)(n0 + n) * 128];
    for (int j8 = q; j8 < 16; j8 += 4)
      *(f16x8*)&sA[n * 264 + j8 * 8] = xr[j8];
    for (int j4 = q; j4 < 32; j4 += 4) {
      const float4 b = ar[j4];
      h16* p1 = &sA[n * 264 + 128 + j4 * 4];
      p1[0] = (h16)b.x; p1[1] = (h16)b.y; p1[2] = (h16)b.z; p1[3] = (h16)b.w;
    }
  } else {
    for (int j = q; j < 256; j += 4) sA[n * 264 + j] = (h16)0.f;
  }
  __syncthreads();

  mfma_gemm<64, 128, 256, 264, 4, 1, true, false>(sA, WT + OFF_NODE, bnode,
      [&](int row, int col, float v) {
        if (row < cnt) XNH[(size_t)(n0 + row) * 128 + col] = (h16)v;
      });
}

// ---------------------------------------------------------------------------
// K4: e_mp MLP + classifier. R22 measured-best shape: 128 sorted edges/block,
// 1024 thr, RS=1, B/edge 2.13KB. sF [128][392] 98KB; HC fp32 @byte 34816.
// Grid 3907.
// ---------------------------------------------------------------------------
__global__ __launch_bounds__(1024, 4) void k_empl(
    const int* __restrict__ ES, const int* __restrict__ ET,
    const int* __restrict__ OID, const h16* __restrict__ XNH,
    const h16* __restrict__ EB, const h16* __restrict__ WT,
    const float* __restrict__ bmp1, const float* __restrict__ bmp2,
    const float* __restrict__ bc1,
    const float* __restrict__ Wc2, const float* __restrict__ bc2,
    float* __restrict__ out)
{
  __shared__ __align__(16) h16 sF[128 * 392];
  const int tid = threadIdx.x;
  const long e0 = (long)blockIdx.x * 128;
  const long rem = (long)EE - e0;
  const int cnt = rem < 128 ? (int)rem : 128;
  const int n = tid >> 3;
  const int q = tid & 7;

  if (n < cnt) {
    const int s = ES[e0 + n];
    const int t = ET[e0 + n];
    const f16x8* xsr = (const f16x8*)&XNH[(size_t)s * 128];
    const f16x8* xtr = (const f16x8*)&XNH[(size_t)t * 128];
    const f16x8* ebr = (const f16x8*)&EB[(size_t)(e0 + n) * 128];
#pragma unroll
    for (int j8 = q; j8 < 16; j8 += 8) {
      *(f16x8*)&sF[n * 392 + j8 * 8]       = xsr[j8];
      *(f16x8*)&sF[n * 392 + 128 + j8 * 8] = xtr[j8];
      *(f16x8*)&sF[n * 392 + 256 + j8 * 8] = ebr[j8];
    }
  } else {
    for (int j8 = q; j8 < 49; j8 += 8) *(f16x8*)&sF[n * 392 + j8 * 8] = (f16x8){};
  }
  __syncthreads();

  h16*  sH2 = sF;                              // stride 264
  h16*  sE  = sF;                              // stride 136 (over dead H2)
  float* sHC = (float*)((char*)sF + 34816);    // stride 65 fp32, past sE
  mfma_gemm<128, 256, 384, 392, 16, 1, true, true>(sF, WT + OFF_MP1, bmp1,
      [&](int row, int col, float v) { sH2[row * 264 + col] = (h16)v; });
  mfma_gemm<128, 128, 256, 264, 16, 1, false, true>(sH2, WT + OFF_MP2, bmp2,
      [&](int row, int col, float v) { sE[row * 136 + col] = (h16)v; });
  mfma_gemm<128, 64, 128, 136, 16, 1, true, true>(sE, WT + OFF_C1, bc1,
      [&](int row, int col, float v) { sHC[row * 65 + col] = v; });
  if (tid < cnt) {
    float acc = bc2[0];
    for (int k = 0; k < 64; ++k) acc += sHC[tid * 65 + k] * Wc2[k];
    out[OID[e0 + tid]] = acc;
  }
}

// ---------------------------------------------------------------------------
extern "C" void kernel_launch(void* const* d_in, const int* in_sizes, int n_in,
                              void* d_out, int out_size, void* d_ws, size_t ws_size,
                              hipStream_t stream)
{
  const float* x1  = (const float*)d_in[0];
  const float* x2  = (const float*)d_in[1];
  const int*   ei  = (const int*)d_in[2];
  const float* Wh1 = (const float*)d_in[3],  *bh1 = (const float*)d_in[4];
  const float* Wh2 = (const float*)d_in[5],  *bh2 = (const float*)d_in[6];
  const float* Wl1 = (const float*)d_in[7],  *bl1 = (const float*)d_in[8];
  const float* Wl2 = (const float*)d_in[9],  *bl2 = (const float*)d_in[10];
  const float* We1 = (const float*)d_in[11], *be1 = (const float*)d_in[12];
  const float* We2 = (const float*)d_in[13], *be2 = (const float*)d_in[14];
  const float* Wmsg = (const float*)d_in[15], *bmsg = (const float*)d_in[16];
  const float* Wnode = (const float*)d_in[17], *bnode = (const float*)d_in[18];
  const float* Wmp1 = (const float*)d_in[19], *bmp1 = (const float*)d_in[20];
  const float* Wmp2 = (const float*)d_in[21], *bmp2 = (const float*)d_in[22];
  const float* Wc1 = (const float*)d_in[23], *bc1 = (const float*)d_in[24];
  const float* Wc2 = (const float*)d_in[25], *bc2 = (const float*)d_in[26];
  float* out = (float*)d_out;

  // ws layout (~201MB): AGG|EB|WT|XH|XNH|X1P|X2H|BF|CNT|POS|TEX|ES|ET|OID|BS|BSSE
  float* AGG = (float*)d_ws;
  h16*   EB  = (h16*)(AGG + (size_t)NN * 128);
  h16*   WT  = EB + (size_t)EE * 128;
  h16*   XH  = WT + WT_TOTAL;
  h16*   XNH = XH + (size_t)NN * 128;
  h16*   X1P = XNH + (size_t)NN * 128;
  h16*   X2H = X1P + (size_t)NN * 16;
  float* BF  = (float*)(X2H + (size_t)NN * 128);
  int*   CNT = (int*)(BF + BF_TOTAL);
  int*   POS = CNT + NN;
  int*   TEX = POS + NN;
  int*   ES  = TEX + NN;
  int*   ET  = ES + EE;
  int*   OID = ET + EE;
  int*   BS  = OID + EE;
  int*   BSSE = BS + 256;

  k_prep<<<(WT_TOTAL + BF_TOTAL + 255) / 256, 256, 0, stream>>>(
      We1, We2, Wmsg, Wnode, Wmp1, Wmp2, Wc1,
      Wh1, Wl1, Wh2, Wl2, bh1, bl1, bh2, bl2, WT, BF);
  hipMemsetAsync(AGG, 0, (size_t)NN * 128 * sizeof(float), stream);
  hipMemsetAsync(CNT, 0, (size_t)2 * NN * sizeof(int), stream);  // CNT+POS
  k_cvt<<<(NN * 16 + NN * 128 + 255) / 256, 256, 0, stream>>>(
      x1, x2, ei, X1P, X2H, CNT);
  k_scanA<<<SCAN_B, 256, 0, stream>>>(CNT, TEX, BS);
  k_scanB<<<1, 256, 0, stream>>>(BS, BSSE);
  k_scatter<<<(EE + 255) / 256, 256, 0, stream>>>(ei, TEX, BSSE, POS, ES, ET, OID);
  k_nenc<<<(NN + 31) / 32, 512, 0, stream>>>(X1P, X2H, WT, BF, XH);
  k_edge_mlp<<<PGRID, 512, 0, stream>>>(X1P, X2H, ES, ET, XH, WT,
                                        be1, be2, bmsg, EB, AGG);
  k_node_update<<<782, 256, 0, stream>>>(XH, AGG, WT, bnode, XNH);
  k_empl<<<3907, 1024, 0, stream>>>(ES, ET, OID, XNH, EB, WT, bmp1, bmp2, bc1,
                                    Wc2, bc2, out);
}

// Round 12
// 842.731 us; speedup vs baseline: 1.2127x; 1.2127x over previous
//
#include <hip/hip_runtime.h>
#include <hip/hip_bf16.h>
#include <hip/hip_fp16.h>

// CellTrack GNN, MI355X — R25: R23 base + k_nenc block-diag K-split (zero-work).
// R24 (persistent prefetch) REFUTED: FETCH 156->710MB — short-lived in-order
// blocks ARE the L2 locality mechanism (co-resident set = consecutive sorted
// tiles); persistent blocks drift -> working set spills to HBM. Reverted.
// R25 = R23 (851us best: k_edge_mlp 64e/512t/2blk-CU, k_empl 128e/1024t)
// + k_nenc GEMM2 packed [128][256] (block-diag: cols<32 read hid1 k<256,
// cols>=32 read hid2 k>=256 via per-wave A offset) -> half the MFMA steps
// and half the B traffic of that GEMM. Math identical.
// ws: AGG|EB|WT|XH|XNH|X1P|X2H|BF|CNT|POS|TEX|ES|ET|OID|BS|BSSE ~201MB.

using fp16 = __half;
typedef _Float16 h16;
typedef _Float16 f16x8 __attribute__((ext_vector_type(8)));
typedef _Float16 h16x2 __attribute__((ext_vector_type(2)));
typedef short s16x8 __attribute__((ext_vector_type(8)));
typedef float f32x4 __attribute__((ext_vector_type(4)));

#define NN 50000
#define EE 500000
#define EPSC 1e-8f
#define SCAN_B 196   // ceil(NN/256)

__device__ __forceinline__ float reluf(float v){ return v > 0.f ? v : 0.f; }

__device__ __forceinline__ float dot8(const f16x8 a, const f16x8 b, float acc)
{
#pragma unroll
  for (int i = 0; i < 4; ++i) {
    const h16x2 av = {a[2 * i], a[2 * i + 1]};
    const h16x2 bv = {b[2 * i], b[2 * i + 1]};
    acc = __builtin_amdgcn_fdot2(av, bv, acc, false);
  }
  return acc;
}

__device__ __forceinline__ f16x8 absdiff8(const f16x8 a, const f16x8 b)
{
  const f16x8 d = a - b;
  s16x8 di = __builtin_bit_cast(s16x8, d);
  di &= (short)0x7fff;
  return __builtin_bit_cast(f16x8, di);
}

// WT sub-buffer offsets (halves)
#define OFF_E1   0         // [256][544]  (527 real, permuted col order)
#define OFF_E2   139264    // [128][256]
#define OFF_MSG  172032    // [128][256]  ([e|xs] order)
#define OFF_NODE 204800    // [128][256]
#define OFF_MP1  237568    // [256][384]
#define OFF_MP2  335872    // [128][256]
#define OFF_C1   368640    // [64][128]
#define OFF_N1   376832    // [512][160]  block-diag [Wh1 | Wl1]
#define OFF_N2   458752    // [128][256]  PACKED block-diag: n<32 Wh2(k<256 of hid1), n>=32 Wl2(k of hid2)
#define N2_END   491520    // OFF_N2 + 128*256
#define WT_TOTAL 524288    // tail [N2_END, WT_TOTAL) zero-filled / unused
#define BF_TOTAL 640

// ---------------------------------------------------------------------------
__global__ __launch_bounds__(256) void k_prep(
    const float* __restrict__ We1, const float* __restrict__ We2,
    const float* __restrict__ Wmsg, const float* __restrict__ Wnode,
    const float* __restrict__ Wmp1, const float* __restrict__ Wmp2,
    const float* __restrict__ Wc1,
    const float* __restrict__ Wh1, const float* __restrict__ Wl1,
    const float* __restrict__ Wh2, const float* __restrict__ Wl2,
    const float* __restrict__ bh1, const float* __restrict__ bl1,
    const float* __restrict__ bh2, const float* __restrict__ bl2,
    h16* __restrict__ WT, float* __restrict__ BF)
{
  int idx = blockIdx.x * 256 + threadIdx.x;
  if (idx >= WT_TOTAL) {
    const int b = idx - WT_TOTAL;
    if (b < 512) BF[b] = (b < 256) ? bh1[b] : bl1[b - 256];
    else if (b < BF_TOTAL) {
      const int c = b - 512;
      BF[b] = (c < 32) ? bh2[c] : bl2[c - 32];
    }
    return;
  }
  h16 v;
  if (idx < OFF_E2) {
    const int L = idx, n = L / 544, k = L % 544;
    int r;
    if      (k < 128) r = 142 + k;
    else if (k < 256) r = 270 + (k - 128);
    else if (k < 384) r = 398 + (k - 256);
    else if (k < 512) r = 13 + (k - 384);
    else if (k < 525) r = k - 512;
    else if (k == 528) r = 141;
    else if (k == 529) r = 526;
    else r = -1;
    v = (h16)((r >= 0) ? We1[r * 256 + n] : 0.f);
  } else if (idx < OFF_MSG) {
    const int L = idx - OFF_E2, n = L >> 8, k = L & 255;
    v = (h16)We2[k * 128 + n];
  } else if (idx < OFF_NODE) {
    const int L = idx - OFF_MSG, n = L >> 8, k = L & 255;
    const int ko = (k < 128) ? (128 + k) : (k - 128);   // [e|xs] order
    v = (h16)Wmsg[ko * 128 + n];
  } else if (idx < OFF_MP1) {
    const int L = idx - OFF_NODE, n = L >> 8, k = L & 255;
    v = (h16)Wnode[k * 128 + n];
  } else if (idx < OFF_MP2) {
    const int L = idx - OFF_MP1, n = L / 384, k = L % 384;
    v = (h16)Wmp1[k * 256 + n];
  } else if (idx < OFF_C1) {
    const int L = idx - OFF_MP2, n = L >> 8, k = L & 255;
    v = (h16)Wmp2[k * 128 + n];
  } else if (idx < OFF_N1) {
    const int L = idx - OFF_C1, n = L >> 7, k = L & 127;
    v = (h16)Wc1[k * 64 + n];
  } else if (idx < OFF_N2) {
    const int L = idx - OFF_N1, n = L / 160, k = L % 160;
    float f = 0.f;
    if (n < 256) { if (k < 13) f = Wh1[k * 256 + n]; }
    else { if (k >= 16 && k < 144) f = Wl1[(k - 16) * 256 + (n - 256)]; }
    v = (h16)f;
  } else if (idx < N2_END) {
    // packed N2 [128][256]: n<32 -> Wh2[k][n] (k over hid1); n>=32 -> Wl2[k][n-32] (k over hid2)
    const int L = idx - OFF_N2, n = L >> 8, k = L & 255;
    v = (h16)((n < 32) ? Wh2[k * 32 + n] : Wl2[k * 96 + (n - 32)]);
  } else {
    v = (h16)0.f;   // unused tail
  }
  WT[idx] = v;
}

// k_cvt: x1 -> fp16 mirror padded to 16/row, x2 -> fp16; + trg histogram.
__global__ __launch_bounds__(256) void k_cvt(
    const float* __restrict__ x1, const float* __restrict__ x2,
    const int* __restrict__ ei,
    h16* __restrict__ X1P, h16* __restrict__ X2H, int* __restrict__ CNT)
{
  const int idx = blockIdx.x * 256 + threadIdx.x;
  if (idx < EE) atomicAdd(&CNT[ei[EE + idx]], 1);
  if (idx < NN * 16) {
    const int nn = idx >> 4, j = idx & 15;
    X1P[idx] = (h16)((j < 13) ? x1[nn * 13 + j] : 0.f);
  }
  const int i2 = idx - NN * 16;
  if (i2 >= 0 && i2 < NN * 128) X2H[i2] = (h16)x2[i2];
}

// --------------------------- hierarchical scan -----------------------------
__global__ __launch_bounds__(256) void k_scanA(
    const int* __restrict__ CNT, int* __restrict__ TEX, int* __restrict__ BS)
{
  __shared__ int sd[256];
  const int tid = threadIdx.x;
  const int i = blockIdx.x * 256 + tid;
  const int v = (i < NN) ? CNT[i] : 0;
  sd[tid] = v;
  __syncthreads();
  for (int off = 1; off < 256; off <<= 1) {
    const int x = (tid >= off) ? sd[tid - off] : 0;
    __syncthreads();
    sd[tid] += x;
    __syncthreads();
  }
  if (i < NN) TEX[i] = sd[tid] - v;
  if (tid == 255) BS[blockIdx.x] = sd[255];
}

__global__ __launch_bounds__(256) void k_scanB(
    const int* __restrict__ BS, int* __restrict__ BSSE)
{
  __shared__ int sd[256];
  const int tid = threadIdx.x;
  const int v = (tid < SCAN_B) ? BS[tid] : 0;
  sd[tid] = v;
  __syncthreads();
  for (int off = 1; off < 256; off <<= 1) {
    const int x = (tid >= off) ? sd[tid - off] : 0;
    __syncthreads();
    sd[tid] += x;
    __syncthreads();
  }
  if (tid < SCAN_B) BSSE[tid] = sd[tid] - v;
}

__global__ __launch_bounds__(256) void k_scatter(
    const int* __restrict__ ei, const int* __restrict__ TEX,
    const int* __restrict__ BSSE, int* __restrict__ POS,
    int* __restrict__ ES, int* __restrict__ ET, int* __restrict__ OID)
{
  const int e = blockIdx.x * 256 + threadIdx.x;
  if (e >= EE) return;
  const int t = ei[EE + e];
  const int p = atomicAdd(&POS[t], 1);
  const int idx = BSSE[t >> 8] + TEX[t] + p;
  ES[idx] = ei[e];
  ET[idx] = t;
  OID[idx] = e;
}

// ---------------------------------------------------------------------------
// MFMA GEMM: C[ROWS][UDIM] = act(A[ROWS][KP] @ WT^T + b). RS=1 everywhere.
// ACOLS/AOFF: block-diag A-split — waves whose col group n0 >= ACOLS read A
// at column offset AOFF (used by k_nenc GEMM2: cols<32 read hid1, else hid2).
// ---------------------------------------------------------------------------
template<int ROWS, int UDIM, int KP, int LDA, int WAVES, int RS, bool RELU,
         bool ENDSYNC, int ACOLS = 0, int AOFF = 0, typename F>
__device__ __forceinline__ void mfma_gemm(const h16* sA,
    const h16* __restrict__ WT, const float* __restrict__ bias, F emit)
{
  constexpr int CS = WAVES / RS;
  constexpr int RG = ROWS / RS;
  constexpr int RT = RG / 16;
  constexpr int NPW0 = UDIM / CS;
  constexpr int NPW = (NPW0 < 16) ? 16 : NPW0;
  constexpr int NT = NPW / 16;
  constexpr int NSTEPS = KP / 32;
  constexpr int CH0 = (NT >= 8) ? 1 : ((NT >= 4) ? 2 : 4);
  constexpr int CHUNK = (NSTEPS < CH0) ? NSTEPS : CH0;
  constexpr int NCH = (NSTEPS + CHUNK - 1) / CHUNK;
  const int tid = threadIdx.x;
  const int wave = tid >> 6;
  const int lane = tid & 63;
  const int m = lane & 15;
  const int quad = lane >> 4;
  const int wr = wave % RS;
  const int wc = wave / RS;
  const int rbase = wr * RG;
  const int n0 = wc * NPW;
  const bool active = (n0 < UDIM);
  const int aoff = (ACOLS > 0 && n0 >= ACOLS) ? AOFF : 0;

  f32x4 acc[RT][NT];
#pragma unroll
  for (int r = 0; r < RT; ++r)
#pragma unroll
    for (int j = 0; j < NT; ++j) acc[r][j] = (f32x4){0.f, 0.f, 0.f, 0.f};
  float bb[NT];

  if (active) {
    const h16* wbase = &WT[(size_t)(n0 + m) * KP + quad * 8];
#pragma unroll
    for (int j = 0; j < NT; ++j) bb[j] = bias[n0 + j * 16 + m];

    f16x8 breg[2][CHUNK][NT];
#pragma unroll
    for (int s = 0; s < CHUNK; ++s)
      if (s < NSTEPS)
#pragma unroll
        for (int j = 0; j < NT; ++j)
          breg[0][s][j] = *(const f16x8*)&wbase[(size_t)j * 16 * KP + s * 32];
    asm volatile("" ::: "memory");

#pragma unroll
    for (int c = 0; c < NCH; ++c) {
      if (c + 1 < NCH) {
#pragma unroll
        for (int s = 0; s < CHUNK; ++s) {
          const int st = (c + 1) * CHUNK + s;
          if (st < NSTEPS)
#pragma unroll
            for (int j = 0; j < NT; ++j)
              breg[(c + 1) & 1][s][j] =
                  *(const f16x8*)&wbase[(size_t)j * 16 * KP + st * 32];
        }
      }
#pragma unroll
      for (int s = 0; s < CHUNK; ++s) {
        const int st = c * CHUNK + s;
        if (st < NSTEPS) {
          const int k0 = st * 32;
#pragma unroll
          for (int r = 0; r < RT; ++r) {
            const f16x8 af = *(const f16x8*)&sA[(rbase + r * 16 + m) * LDA + aoff + k0 + quad * 8];
#pragma unroll
            for (int j = 0; j < NT; ++j)
              acc[r][j] = __builtin_amdgcn_mfma_f32_16x16x32_f16(af, breg[c & 1][s][j], acc[r][j], 0, 0, 0);
          }
        }
      }
      asm volatile("" ::: "memory");
    }
  }
  __syncthreads();
  if (active) {
#pragma unroll
    for (int j = 0; j < NT; ++j) {
      const int col = n0 + j * 16 + m;
#pragma unroll
      for (int r = 0; r < RT; ++r)
#pragma unroll
        for (int g = 0; g < 4; ++g) {
          const int row = rbase + r * 16 + quad * 4 + g;
          float v = acc[r][j][g] + bb[j];
          if (RELU) v = reluf(v);
          emit(row, col, v);
        }
    }
  }
  if (ENDSYNC) __syncthreads();
}

// ---------------------------------------------------------------------------
// K0: node encoder via MFMA. 32 nodes/block, 512 thr (grid 1563, last 16).
// GEMM2 uses packed block-diag N2 [128][256]: cols<32 consume hid1 (A off 0),
// cols>=32 consume hid2 (A off 256) — half the K-steps and B bytes.
// ---------------------------------------------------------------------------
__global__ __launch_bounds__(512, 4) void k_nenc(
    const h16* __restrict__ X1P, const h16* __restrict__ X2H,
    const h16* __restrict__ WT, const float* __restrict__ BF,
    h16* __restrict__ XH)
{
  __shared__ __align__(16) h16 sA[32 * 168];
  __shared__ __align__(16) h16 sH[32 * 520];
  const int tid = threadIdx.x;
  const int n0 = blockIdx.x * 32;
  const int remn = NN - n0;
  const int cnt = remn < 32 ? remn : 32;
  const int n = tid >> 4;
  const int q = tid & 15;

  if (n < cnt) {
    const int node = n0 + n;
    if (q < 2)
      *(f16x8*)&sA[n * 168 + q * 8] = *(const f16x8*)&X1P[node * 16 + q * 8];
    else if (q < 4)
      *(f16x8*)&sA[n * 168 + 144 + (q - 2) * 8] = (f16x8){};
    *(f16x8*)&sA[n * 168 + 16 + q * 8] =
        *(const f16x8*)&X2H[(size_t)node * 128 + q * 8];
  }
  __syncthreads();

  mfma_gemm<32, 512, 160, 168, 8, 1, true, true>(sA, WT + OFF_N1, BF,
      [&](int row, int col, float v) { sH[row * 520 + col] = (h16)v; });
  mfma_gemm<32, 128, 256, 520, 8, 1, false, false, 32, 256>(sH, WT + OFF_N2, BF + 512,
      [&](int row, int col, float v) {
        if (row < cnt) XH[(size_t)(n0 + row) * 128 + col] = (h16)v;
      });
}

// ---------------------------------------------------------------------------
// K2: FUSED edge features + e-MLP + msg GEMM + in-block segment reduce.
// R20/R23 measured-best shape: 64 sorted edges/block, 512 thr (8 waves),
// 2 blk/CU (phase-slide overlap). Grid 7813.
// ---------------------------------------------------------------------------
__global__ __launch_bounds__(512, 4) void k_edge_mlp(
    const h16* __restrict__ X1P, const h16* __restrict__ X2H,
    const int* __restrict__ ES, const int* __restrict__ ET,
    const h16* __restrict__ XH, const h16* __restrict__ WT,
    const float* __restrict__ be1, const float* __restrict__ be2,
    const float* __restrict__ bmsg,
    h16* __restrict__ EB, float* __restrict__ AGG)
{
  __shared__ __align__(16) h16 sFeat[64 * 568];
  __shared__ int strg[64];
  const int tid = threadIdx.x;
  const long e0 = (long)blockIdx.x * 64;
  const long rem = (long)EE - e0;
  const int cnt = rem < 64 ? (int)rem : 64;
  const int n = tid >> 3;
  const int q = tid & 7;
  h16* Arow = &sFeat[n * 568];
  f16x8 xsv0 = {}, xsv1 = {};

  if (n < cnt) {
    const int s = ES[e0 + n];
    const int t = ET[e0 + n];
    if (q == 0) strg[n] = t;
    float ds = 0.f, ns = 0.f, nt = 0.f;
    if (q < 2) {
      const f16x8 a = *(const f16x8*)&X1P[s * 16 + q * 8];
      const f16x8 b = *(const f16x8*)&X1P[t * 16 + q * 8];
      ds = dot8(a, b, ds); ns = dot8(a, a, ns); nt = dot8(b, b, nt);
      *(f16x8*)&Arow[512 + q * 8] = absdiff8(a, b);
    }
#pragma unroll
    for (int c = 0; c < 2; ++c) {
      const f16x8 a = *(const f16x8*)&X2H[(size_t)s * 128 + q * 16 + c * 8];
      const f16x8 b = *(const f16x8*)&X2H[(size_t)t * 128 + q * 16 + c * 8];
      ds = dot8(a, b, ds); ns = dot8(a, a, ns); nt = dot8(b, b, nt);
      *(f16x8*)&Arow[384 + q * 16 + c * 8] = absdiff8(a, b);
    }
    ds += __shfl_xor(ds, 1); ds += __shfl_xor(ds, 2); ds += __shfl_xor(ds, 4);
    ns += __shfl_xor(ns, 1); ns += __shfl_xor(ns, 2); ns += __shfl_xor(ns, 4);
    nt += __shfl_xor(nt, 1); nt += __shfl_xor(nt, 2); nt += __shfl_xor(nt, 4);
    if (q == 0)
      Arow[528] = (h16)(ds / (fmaxf(sqrtf(ns), EPSC) * fmaxf(sqrtf(nt), EPSC)));

    float ds2 = 0.f, ns2 = 0.f, nt2 = 0.f;
#pragma unroll
    for (int c = 0; c < 2; ++c) {
      const f16x8 a = *(const f16x8*)&XH[(size_t)s * 128 + q * 16 + c * 8];
      const f16x8 b = *(const f16x8*)&XH[(size_t)t * 128 + q * 16 + c * 8];
      if (c == 0) xsv0 = a; else xsv1 = a;
      ds2 = dot8(a, b, ds2); ns2 = dot8(a, a, ns2); nt2 = dot8(b, b, nt2);
      *(f16x8*)&Arow[q * 16 + c * 8]       = a;
      *(f16x8*)&Arow[128 + q * 16 + c * 8] = b;
      *(f16x8*)&Arow[256 + q * 16 + c * 8] = absdiff8(a, b);
    }
    ds2 += __shfl_xor(ds2, 1); ds2 += __shfl_xor(ds2, 2); ds2 += __shfl_xor(ds2, 4);
    ns2 += __shfl_xor(ns2, 1); ns2 += __shfl_xor(ns2, 2); ns2 += __shfl_xor(ns2, 4);
    nt2 += __shfl_xor(nt2, 1); nt2 += __shfl_xor(nt2, 2); nt2 += __shfl_xor(nt2, 4);
    if (q == 0)
      Arow[529] = (h16)(ds2 / (fmaxf(sqrtf(ns2), EPSC) * fmaxf(sqrtf(nt2), EPSC)));
    for (int j = 530 + q; j < 544; j += 8) Arow[j] = (h16)0.f;
  } else {
    if (q == 0) strg[n] = 0;
    for (int j8 = q; j8 < 71; j8 += 8) *(f16x8*)&Arow[j8 * 8] = (f16x8){};
  }
  __syncthreads();

  h16* sHid = sFeat;   // stride 264, overlays features (post-barrier)
  mfma_gemm<64, 256, 544, 568, 8, 1, true, true>(sFeat, WT + OFF_E1, be1,
      [&](int row, int col, float v) { sHid[row * 264 + col] = (h16)v; });
  mfma_gemm<64, 128, 256, 264, 8, 1, false, false>(sHid, WT + OFF_E2, be2,
      [&](int row, int col, float v) {
        const h16 vh = (h16)v;
        if (row < cnt) EB[(size_t)(e0 + row) * 128 + col] = vh;
        sHid[row * 264 + col] = vh;                // e at cols [0,128)
      });
  // park xs beside e at cols [128,256): same post-A-read window as GEMM2 emit
  *(f16x8*)&sFeat[n * 264 + 128 + q * 16]     = xsv0;
  *(f16x8*)&sFeat[n * 264 + 128 + q * 16 + 8] = xsv1;
  __syncthreads();
  // msg GEMM: emit fp32 into the (dead, post-barrier) A region, stride 528B
  mfma_gemm<64, 128, 256, 264, 8, 1, true, true>(sFeat, WT + OFF_MSG, bmsg,
      [&](int row, int col, float v) {
        *(float*)((char*)sFeat + row * 528 + col * 4) = v;
      });
  // segment reduction: sorted trg -> runs; 4 row-groups x 128 cols
  {
    const int c = tid & 127;
    const int g = tid >> 7;
    const int r0 = g * 16;
    if (r0 < cnt) {
      const int rend = (r0 + 16 < cnt) ? r0 + 16 : cnt;
      float acc = 0.f;
      int cur = strg[r0];
      for (int r = r0; r < rend; ++r) {
        const int t = strg[r];
        if (t != cur) {
          atomicAdd(&AGG[(size_t)cur * 128 + c], acc);
          acc = 0.f; cur = t;
        }
        acc += *(const float*)((const char*)sFeat + r * 528 + c * 4);
      }
      atomicAdd(&AGG[(size_t)cur * 128 + c], acc);
    }
  }
}

// ---------------------------------------------------------------------------
// K3: xn = relu([x|agg] @ Wnode + b). 64 nodes/block.
// ---------------------------------------------------------------------------
__global__ __launch_bounds__(256, 4) void k_node_update(
    const h16* __restrict__ XH, const float* __restrict__ AGG,
    const h16* __restrict__ WT, const float* __restrict__ bnode,
    h16* __restrict__ XNH)
{
  __shared__ __align__(16) h16 sA[64 * 264];
  const int tid = threadIdx.x;
  const int n0 = blockIdx.x * 64;
  const int remn = NN - n0;
  const int cnt = remn < 64 ? remn : 64;
  const int n = tid >> 2;
  const int q = tid & 3;

  if (n < cnt) {
    const f16x8* xr = (const f16x8*)&XH[(size_t)(n0 + n) * 128];
    const float4* ar = (const float4*)&AGG[(size_t)(n0 + n) * 128];
    for (int j8 = q; j8 < 16; j8 += 4)
      *(f16x8*)&sA[n * 264 + j8 * 8] = xr[j8];
    for (int j4 = q; j4 < 32; j4 += 4) {
      const float4 b = ar[j4];
      h16* p1 = &sA[n * 264 + 128 + j4 * 4];
      p1[0] = (h16)b.x; p1[1] = (h16)b.y; p1[2] = (h16)b.z; p1[3] = (h16)b.w;
    }
  } else {
    for (int j = q; j < 256; j += 4) sA[n * 264 + j] = (h16)0.f;
  }
  __syncthreads();

  mfma_gemm<64, 128, 256, 264, 4, 1, true, false>(sA, WT + OFF_NODE, bnode,
      [&](int row, int col, float v) {
        if (row < cnt) XNH[(size_t)(n0 + row) * 128 + col] = (h16)v;
      });
}

// ---------------------------------------------------------------------------
// K4: e_mp MLP + classifier. R22 measured-best shape: 128 sorted edges/block,
// 1024 thr, RS=1, B/edge 2.13KB. sF [128][392] 98KB; HC fp32 @byte 34816.
// Grid 3907.
// ---------------------------------------------------------------------------
__global__ __launch_bounds__(1024, 4) void k_empl(
    const int* __restrict__ ES, const int* __restrict__ ET,
    const int* __restrict__ OID, const h16* __restrict__ XNH,
    const h16* __restrict__ EB, const h16* __restrict__ WT,
    const float* __restrict__ bmp1, const float* __restrict__ bmp2,
    const float* __restrict__ bc1,
    const float* __restrict__ Wc2, const float* __restrict__ bc2,
    float* __restrict__ out)
{
  __shared__ __align__(16) h16 sF[128 * 392];
  const int tid = threadIdx.x;
  const long e0 = (long)blockIdx.x * 128;
  const long rem = (long)EE - e0;
  const int cnt = rem < 128 ? (int)rem : 128;
  const int n = tid >> 3;
  const int q = tid & 7;

  if (n < cnt) {
    const int s = ES[e0 + n];
    const int t = ET[e0 + n];
    const f16x8* xsr = (const f16x8*)&XNH[(size_t)s * 128];
    const f16x8* xtr = (const f16x8*)&XNH[(size_t)t * 128];
    const f16x8* ebr = (const f16x8*)&EB[(size_t)(e0 + n) * 128];
#pragma unroll
    for (int j8 = q; j8 < 16; j8 += 8) {
      *(f16x8*)&sF[n * 392 + j8 * 8]       = xsr[j8];
      *(f16x8*)&sF[n * 392 + 128 + j8 * 8] = xtr[j8];
      *(f16x8*)&sF[n * 392 + 256 + j8 * 8] = ebr[j8];
    }
  } else {
    for (int j8 = q; j8 < 49; j8 += 8) *(f16x8*)&sF[n * 392 + j8 * 8] = (f16x8){};
  }
  __syncthreads();

  h16*  sH2 = sF;                              // stride 264
  h16*  sE  = sF;                              // stride 136 (over dead H2)
  float* sHC = (float*)((char*)sF + 34816);    // stride 65 fp32, past sE
  mfma_gemm<128, 256, 384, 392, 16, 1, true, true>(sF, WT + OFF_MP1, bmp1,
      [&](int row, int col, float v) { sH2[row * 264 + col] = (h16)v; });
  mfma_gemm<128, 128, 256, 264, 16, 1, false, true>(sH2, WT + OFF_MP2, bmp2,
      [&](int row, int col, float v) { sE[row * 136 + col] = (h16)v; });
  mfma_gemm<128, 64, 128, 136, 16, 1, true, true>(sE, WT + OFF_C1, bc1,
      [&](int row, int col, float v) { sHC[row * 65 + col] = v; });
  if (tid < cnt) {
    float acc = bc2[0];
    for (int k = 0; k < 64; ++k) acc += sHC[tid * 65 + k] * Wc2[k];
    out[OID[e0 + tid]] = acc;
  }
}

// ---------------------------------------------------------------------------
extern "C" void kernel_launch(void* const* d_in, const int* in_sizes, int n_in,
                              void* d_out, int out_size, void* d_ws, size_t ws_size,
                              hipStream_t stream)
{
  const float* x1  = (const float*)d_in[0];
  const float* x2  = (const float*)d_in[1];
  const int*   ei  = (const int*)d_in[2];
  const float* Wh1 = (const float*)d_in[3],  *bh1 = (const float*)d_in[4];
  const float* Wh2 = (const float*)d_in[5],  *bh2 = (const float*)d_in[6];
  const float* Wl1 = (const float*)d_in[7],  *bl1 = (const float*)d_in[8];
  const float* Wl2 = (const float*)d_in[9],  *bl2 = (const float*)d_in[10];
  const float* We1 = (const float*)d_in[11], *be1 = (const float*)d_in[12];
  const float* We2 = (const float*)d_in[13], *be2 = (const float*)d_in[14];
  const float* Wmsg = (const float*)d_in[15], *bmsg = (const float*)d_in[16];
  const float* Wnode = (const float*)d_in[17], *bnode = (const float*)d_in[18];
  const float* Wmp1 = (const float*)d_in[19], *bmp1 = (const float*)d_in[20];
  const float* Wmp2 = (const float*)d_in[21], *bmp2 = (const float*)d_in[22];
  const float* Wc1 = (const float*)d_in[23], *bc1 = (const float*)d_in[24];
  const float* Wc2 = (const float*)d_in[25], *bc2 = (const float*)d_in[26];
  float* out = (float*)d_out;

  // ws layout (~201MB): AGG|EB|WT|XH|XNH|X1P|X2H|BF|CNT|POS|TEX|ES|ET|OID|BS|BSSE
  float* AGG = (float*)d_ws;
  h16*   EB  = (h16*)(AGG + (size_t)NN * 128);
  h16*   WT  = EB + (size_t)EE * 128;
  h16*   XH  = WT + WT_TOTAL;
  h16*   XNH = XH + (size_t)NN * 128;
  h16*   X1P = XNH + (size_t)NN * 128;
  h16*   X2H = X1P + (size_t)NN * 16;
  float* BF  = (float*)(X2H + (size_t)NN * 128);
  int*   CNT = (int*)(BF + BF_TOTAL);
  int*   POS = CNT + NN;
  int*   TEX = POS + NN;
  int*   ES  = TEX + NN;
  int*   ET  = ES + EE;
  int*   OID = ET + EE;
  int*   BS  = OID + EE;
  int*   BSSE = BS + 256;

  k_prep<<<(WT_TOTAL + BF_TOTAL + 255) / 256, 256, 0, stream>>>(
      We1, We2, Wmsg, Wnode, Wmp1, Wmp2, Wc1,
      Wh1, Wl1, Wh2, Wl2, bh1, bl1, bh2, bl2, WT, BF);
  hipMemsetAsync(AGG, 0, (size_t)NN * 128 * sizeof(float), stream);
  hipMemsetAsync(CNT, 0, (size_t)2 * NN * sizeof(int), stream);  // CNT+POS
  k_cvt<<<(NN * 16 + NN * 128 + 255) / 256, 256, 0, stream>>>(
      x1, x2, ei, X1P, X2H, CNT);
  k_scanA<<<SCAN_B, 256, 0, stream>>>(CNT, TEX, BS);
  k_scanB<<<1, 256, 0, stream>>>(BS, BSSE);
  k_scatter<<<(EE + 255) / 256, 256, 0, stream>>>(ei, TEX, BSSE, POS, ES, ET, OID);
  k_nenc<<<(NN + 31) / 32, 512, 0, stream>>>(X1P, X2H, WT, BF, XH);
  k_edge_mlp<<<7813, 512, 0, stream>>>(X1P, X2H, ES, ET, XH, WT,
                                       be1, be2, bmsg, EB, AGG);
  k_node_update<<<782, 256, 0, stream>>>(XH, AGG, WT, bnode, XNH);
  k_empl<<<3907, 1024, 0, stream>>>(ES, ET, OID, XNH, EB, WT, bmp1, bmp2, bc1,
                                    Wc2, bc2, out);
}

// Round 13
// 799.259 us; speedup vs baseline: 1.2787x; 1.0544x over previous
//
#include <hip/hip_runtime.h>
#include <hip/hip_bf16.h>
#include <hip/hip_fp16.h>

// CellTrack GNN, MI355X — R26: k_empl 2-phase MP1 (LDS 98->68KB, 2 blk/CU) +
// launch fusion (11 -> 8 dispatches).
// R25 (843us best): k_edge_mlp 377 at its structure plateau; k_empl est ~250us
// at 1 blk/CU (98KB LDS) -> no phase-slide overlap (the R22/R23 mechanism).
// R26: MP1 K=384 split into K=256 ([xn_s|xn_t]) + K=128 (e staged mid-kernel
// into the dead A cols) accumulating one acc -> A buffer [128][264], LDS
// 67.6KB, launch_bounds(1024,8) targets 2 blk/CU (needs VGPR<=64; CHUNK=2).
// Wmp1 repacked MP1A[256][256]+MP1B[256][128]. Fusions: CNT/POS zero ->
// k_prep; AGG zero -> k_cvt; k_scanB -> per-block scan in k_scatter.
// ws: AGG|EB|WT|XH|XNH|X1P|X2H|BF|CNT|POS|TEX|ES|ET|OID|BS ~201MB.

using fp16 = __half;
typedef _Float16 h16;
typedef _Float16 f16x8 __attribute__((ext_vector_type(8)));
typedef _Float16 h16x2 __attribute__((ext_vector_type(2)));
typedef short s16x8 __attribute__((ext_vector_type(8)));
typedef float f32x4 __attribute__((ext_vector_type(4)));

#define NN 50000
#define EE 500000
#define EPSC 1e-8f
#define SCAN_B 196   // ceil(NN/256)

__device__ __forceinline__ float reluf(float v){ return v > 0.f ? v : 0.f; }

__device__ __forceinline__ float dot8(const f16x8 a, const f16x8 b, float acc)
{
#pragma unroll
  for (int i = 0; i < 4; ++i) {
    const h16x2 av = {a[2 * i], a[2 * i + 1]};
    const h16x2 bv = {b[2 * i], b[2 * i + 1]};
    acc = __builtin_amdgcn_fdot2(av, bv, acc, false);
  }
  return acc;
}

__device__ __forceinline__ f16x8 absdiff8(const f16x8 a, const f16x8 b)
{
  const f16x8 d = a - b;
  s16x8 di = __builtin_bit_cast(s16x8, d);
  di &= (short)0x7fff;
  return __builtin_bit_cast(f16x8, di);
}

// WT sub-buffer offsets (halves)
#define OFF_E1   0         // [256][544]  (527 real, permuted col order)
#define OFF_E2   139264    // [128][256]
#define OFF_MSG  172032    // [128][256]  ([e|xs] order)
#define OFF_NODE 204800    // [128][256]
#define OFF_MP1  237568    // MP1A [256][256]  (k over [xn_s|xn_t])
#define OFF_MP1B 303104    // MP1B [256][128]  (k over e)
#define OFF_MP2  335872    // [128][256]
#define OFF_C1   368640    // [64][128]
#define OFF_N1   376832    // [512][160]  block-diag [Wh1 | Wl1]
#define OFF_N2   458752    // [128][256]  packed block-diag (R25)
#define N2_END   491520
#define WT_TOTAL 524288
#define BF_TOTAL 640

// ---------------------------------------------------------------------------
// k_prep: fp32 weights -> fp16 transposed; also zeroes CNT+POS (2*NN ints).
// ---------------------------------------------------------------------------
__global__ __launch_bounds__(256) void k_prep(
    const float* __restrict__ We1, const float* __restrict__ We2,
    const float* __restrict__ Wmsg, const float* __restrict__ Wnode,
    const float* __restrict__ Wmp1, const float* __restrict__ Wmp2,
    const float* __restrict__ Wc1,
    const float* __restrict__ Wh1, const float* __restrict__ Wl1,
    const float* __restrict__ Wh2, const float* __restrict__ Wl2,
    const float* __restrict__ bh1, const float* __restrict__ bl1,
    const float* __restrict__ bh2, const float* __restrict__ bl2,
    h16* __restrict__ WT, float* __restrict__ BF, int* __restrict__ CNT)
{
  int idx = blockIdx.x * 256 + threadIdx.x;
  if (idx < 2 * NN) CNT[idx] = 0;           // CNT + POS (contiguous)
  if (idx >= WT_TOTAL) {
    const int b = idx - WT_TOTAL;
    if (b < 512) BF[b] = (b < 256) ? bh1[b] : bl1[b - 256];
    else if (b < BF_TOTAL) {
      const int c = b - 512;
      BF[b] = (c < 32) ? bh2[c] : bl2[c - 32];
    }
    return;
  }
  h16 v;
  if (idx < OFF_E2) {
    const int L = idx, n = L / 544, k = L % 544;
    int r;
    if      (k < 128) r = 142 + k;
    else if (k < 256) r = 270 + (k - 128);
    else if (k < 384) r = 398 + (k - 256);
    else if (k < 512) r = 13 + (k - 384);
    else if (k < 525) r = k - 512;
    else if (k == 528) r = 141;
    else if (k == 529) r = 526;
    else r = -1;
    v = (h16)((r >= 0) ? We1[r * 256 + n] : 0.f);
  } else if (idx < OFF_MSG) {
    const int L = idx - OFF_E2, n = L >> 8, k = L & 255;
    v = (h16)We2[k * 128 + n];
  } else if (idx < OFF_NODE) {
    const int L = idx - OFF_MSG, n = L >> 8, k = L & 255;
    const int ko = (k < 128) ? (128 + k) : (k - 128);   // [e|xs] order
    v = (h16)Wmsg[ko * 128 + n];
  } else if (idx < OFF_MP1) {
    const int L = idx - OFF_NODE, n = L >> 8, k = L & 255;
    v = (h16)Wnode[k * 128 + n];
  } else if (idx < OFF_MP1B) {              // MP1A [256][256]: k over xn_s|xn_t
    const int L = idx - OFF_MP1, n = L >> 8, k = L & 255;
    v = (h16)Wmp1[k * 256 + n];
  } else if (idx < OFF_MP2) {               // MP1B [256][128]: k over e
    const int L = idx - OFF_MP1B, n = L >> 7, k = L & 127;
    v = (h16)Wmp1[(256 + k) * 256 + n];
  } else if (idx < OFF_C1) {
    const int L = idx - OFF_MP2, n = L >> 8, k = L & 255;
    v = (h16)Wmp2[k * 128 + n];
  } else if (idx < OFF_N1) {
    const int L = idx - OFF_C1, n = L >> 7, k = L & 127;
    v = (h16)Wc1[k * 64 + n];
  } else if (idx < OFF_N2) {
    const int L = idx - OFF_N1, n = L / 160, k = L % 160;
    float f = 0.f;
    if (n < 256) { if (k < 13) f = Wh1[k * 256 + n]; }
    else { if (k >= 16 && k < 144) f = Wl1[(k - 16) * 256 + (n - 256)]; }
    v = (h16)f;
  } else if (idx < N2_END) {
    const int L = idx - OFF_N2, n = L >> 8, k = L & 255;
    v = (h16)((n < 32) ? Wh2[k * 32 + n] : Wl2[k * 96 + (n - 32)]);
  } else {
    v = (h16)0.f;
  }
  WT[idx] = v;
}

// k_cvt: fp16 mirrors + trg histogram + AGG zero-fill (fused).
__global__ __launch_bounds__(256) void k_cvt(
    const float* __restrict__ x1, const float* __restrict__ x2,
    const int* __restrict__ ei,
    h16* __restrict__ X1P, h16* __restrict__ X2H, int* __restrict__ CNT,
    float* __restrict__ AGG)
{
  const int idx = blockIdx.x * 256 + threadIdx.x;
  if (idx < EE) atomicAdd(&CNT[ei[EE + idx]], 1);
  if (idx < NN * 128) AGG[idx] = 0.f;
  if (idx < NN * 16) {
    const int nn = idx >> 4, j = idx & 15;
    X1P[idx] = (h16)((j < 13) ? x1[nn * 13 + j] : 0.f);
  }
  const int i2 = idx - NN * 16;
  if (i2 >= 0 && i2 < NN * 128) X2H[i2] = (h16)x2[i2];
}

// --------------------------- hierarchical scan -----------------------------
__global__ __launch_bounds__(256) void k_scanA(
    const int* __restrict__ CNT, int* __restrict__ TEX, int* __restrict__ BS)
{
  __shared__ int sd[256];
  const int tid = threadIdx.x;
  const int i = blockIdx.x * 256 + tid;
  const int v = (i < NN) ? CNT[i] : 0;
  sd[tid] = v;
  __syncthreads();
  for (int off = 1; off < 256; off <<= 1) {
    const int x = (tid >= off) ? sd[tid - off] : 0;
    __syncthreads();
    sd[tid] += x;
    __syncthreads();
  }
  if (i < NN) TEX[i] = sd[tid] - v;
  if (tid == 255) BS[blockIdx.x] = sd[255];
}

// k_scatter: per-block exclusive scan of BS (196 entries) in LDS, then scatter.
__global__ __launch_bounds__(256) void k_scatter(
    const int* __restrict__ ei, const int* __restrict__ TEX,
    const int* __restrict__ BS, int* __restrict__ POS,
    int* __restrict__ ES, int* __restrict__ ET, int* __restrict__ OID)
{
  __shared__ int sbase[256];
  const int tid = threadIdx.x;
  const int v = (tid < SCAN_B) ? BS[tid] : 0;
  sbase[tid] = v;
  __syncthreads();
  for (int off = 1; off < 256; off <<= 1) {
    const int x = (tid >= off) ? sbase[tid - off] : 0;
    __syncthreads();
    sbase[tid] += x;
    __syncthreads();
  }
  const int excl = sbase[tid] - v;
  __syncthreads();
  sbase[tid] = excl;
  __syncthreads();

  const int e = blockIdx.x * 256 + tid;
  if (e >= EE) return;
  const int t = ei[EE + e];
  const int p = atomicAdd(&POS[t], 1);
  const int idx = sbase[t >> 8] + TEX[t] + p;
  ES[idx] = ei[e];
  ET[idx] = t;
  OID[idx] = e;
}

// ---------------------------------------------------------------------------
// chunked B-prefetch GEMM phase: accumulates into acc (shared across phases).
// ---------------------------------------------------------------------------
template<int RT, int NT, int KP, int LDA, int CHUNK>
__device__ __forceinline__ void gemm_phase(const h16* sA, const h16* wbase,
    f32x4 (&acc)[RT][NT], int m, int quad)
{
  constexpr int NSTEPS = KP / 32;
  constexpr int NCH = (NSTEPS + CHUNK - 1) / CHUNK;
  f16x8 breg[2][CHUNK][NT];
#pragma unroll
  for (int s = 0; s < CHUNK; ++s)
    if (s < NSTEPS)
#pragma unroll
      for (int j = 0; j < NT; ++j)
        breg[0][s][j] = *(const f16x8*)&wbase[(size_t)j * 16 * KP + s * 32];
  asm volatile("" ::: "memory");
#pragma unroll
  for (int c = 0; c < NCH; ++c) {
    if (c + 1 < NCH) {
#pragma unroll
      for (int s = 0; s < CHUNK; ++s) {
        const int st = (c + 1) * CHUNK + s;
        if (st < NSTEPS)
#pragma unroll
          for (int j = 0; j < NT; ++j)
            breg[(c + 1) & 1][s][j] =
                *(const f16x8*)&wbase[(size_t)j * 16 * KP + st * 32];
      }
    }
#pragma unroll
    for (int s = 0; s < CHUNK; ++s) {
      const int st = c * CHUNK + s;
      if (st < NSTEPS) {
        const int k0 = st * 32;
#pragma unroll
        for (int r = 0; r < RT; ++r) {
          const f16x8 af = *(const f16x8*)&sA[(r * 16 + m) * LDA + k0 + quad * 8];
#pragma unroll
          for (int j = 0; j < NT; ++j)
            acc[r][j] = __builtin_amdgcn_mfma_f32_16x16x32_f16(af, breg[c & 1][s][j], acc[r][j], 0, 0, 0);
        }
      }
    }
    asm volatile("" ::: "memory");
  }
}

// ---------------------------------------------------------------------------
// MFMA GEMM (R25 body): C[ROWS][UDIM] = act(A[ROWS][KP] @ WT^T + b).
// ---------------------------------------------------------------------------
template<int ROWS, int UDIM, int KP, int LDA, int WAVES, int RS, bool RELU,
         bool ENDSYNC, int ACOLS = 0, int AOFF = 0, typename F>
__device__ __forceinline__ void mfma_gemm(const h16* sA,
    const h16* __restrict__ WT, const float* __restrict__ bias, F emit)
{
  constexpr int CS = WAVES / RS;
  constexpr int RG = ROWS / RS;
  constexpr int RT = RG / 16;
  constexpr int NPW0 = UDIM / CS;
  constexpr int NPW = (NPW0 < 16) ? 16 : NPW0;
  constexpr int NT = NPW / 16;
  constexpr int NSTEPS = KP / 32;
  constexpr int CH0 = (NT >= 8) ? 1 : ((NT >= 4) ? 2 : 4);
  constexpr int CHUNK = (NSTEPS < CH0) ? NSTEPS : CH0;
  const int tid = threadIdx.x;
  const int wave = tid >> 6;
  const int lane = tid & 63;
  const int m = lane & 15;
  const int quad = lane >> 4;
  const int wr = wave % RS;
  const int wc = wave / RS;
  const int rbase = wr * RG;
  const int n0 = wc * NPW;
  const bool active = (n0 < UDIM);
  const int aoff = (ACOLS > 0 && n0 >= ACOLS) ? AOFF : 0;

  f32x4 acc[RT][NT];
#pragma unroll
  for (int r = 0; r < RT; ++r)
#pragma unroll
    for (int j = 0; j < NT; ++j) acc[r][j] = (f32x4){0.f, 0.f, 0.f, 0.f};
  float bb[NT];

  if (active) {
    const h16* wbase = &WT[(size_t)(n0 + m) * KP + quad * 8];
#pragma unroll
    for (int j = 0; j < NT; ++j) bb[j] = bias[n0 + j * 16 + m];
    gemm_phase<RT, NT, KP, LDA, CHUNK>(&sA[rbase * LDA + aoff], wbase, acc, m, quad);
  }
  __syncthreads();
  if (active) {
#pragma unroll
    for (int j = 0; j < NT; ++j) {
      const int col = n0 + j * 16 + m;
#pragma unroll
      for (int r = 0; r < RT; ++r)
#pragma unroll
        for (int g = 0; g < 4; ++g) {
          const int row = rbase + r * 16 + quad * 4 + g;
          float v = acc[r][j][g] + bb[j];
          if (RELU) v = reluf(v);
          emit(row, col, v);
        }
    }
  }
  if (ENDSYNC) __syncthreads();
}

// ---------------------------------------------------------------------------
// two-phase GEMM: acc over KP1 (WT1) then stage2() refills A cols and acc
// over KP2 (WT2); single bias+emit. Used by k_empl's MP1 split.
// ---------------------------------------------------------------------------
template<int ROWS, int UDIM, int KP1, int KP2, int LDA, int WAVES, bool RELU,
         typename S, typename F>
__device__ __forceinline__ void mfma_gemm_2p(const h16* sA,
    const h16* __restrict__ WT1, const h16* __restrict__ WT2,
    const float* __restrict__ bias, S stage2, F emit)
{
  constexpr int RT = ROWS / 16;
  constexpr int NPW0 = UDIM / WAVES;
  constexpr int NPW = (NPW0 < 16) ? 16 : NPW0;
  constexpr int NT = NPW / 16;
  const int tid = threadIdx.x;
  const int wave = tid >> 6;
  const int lane = tid & 63;
  const int m = lane & 15;
  const int quad = lane >> 4;
  const int n0 = wave * NPW;
  const bool active = (n0 < UDIM);

  f32x4 acc[RT][NT];
#pragma unroll
  for (int r = 0; r < RT; ++r)
#pragma unroll
    for (int j = 0; j < NT; ++j) acc[r][j] = (f32x4){0.f, 0.f, 0.f, 0.f};
  float bb[NT];

  if (active) {
#pragma unroll
    for (int j = 0; j < NT; ++j) bb[j] = bias[n0 + j * 16 + m];
    gemm_phase<RT, NT, KP1, LDA, 2>(sA,
        &WT1[(size_t)(n0 + m) * KP1 + quad * 8], acc, m, quad);
  }
  __syncthreads();          // all phase-1 A reads done
  stage2();                 // overwrite A cols [0,KP2) with phase-2 operand
  __syncthreads();
  if (active) {
    gemm_phase<RT, NT, KP2, LDA, 2>(sA,
        &WT2[(size_t)(n0 + m) * KP2 + quad * 8], acc, m, quad);
  }
  __syncthreads();          // all phase-2 A reads done -> emits may overlay
  if (active) {
#pragma unroll
    for (int j = 0; j < NT; ++j) {
      const int col = n0 + j * 16 + m;
#pragma unroll
      for (int r = 0; r < RT; ++r)
#pragma unroll
        for (int g = 0; g < 4; ++g) {
          const int row = r * 16 + quad * 4 + g;
          float v = acc[r][j][g] + bb[j];
          if (RELU) v = reluf(v);
          emit(row, col, v);
        }
    }
  }
  __syncthreads();
}

// ---------------------------------------------------------------------------
// K0: node encoder via MFMA. 32 nodes/block, 512 thr (grid 1563, last 16).
// ---------------------------------------------------------------------------
__global__ __launch_bounds__(512, 4) void k_nenc(
    const h16* __restrict__ X1P, const h16* __restrict__ X2H,
    const h16* __restrict__ WT, const float* __restrict__ BF,
    h16* __restrict__ XH)
{
  __shared__ __align__(16) h16 sA[32 * 168];
  __shared__ __align__(16) h16 sH[32 * 520];
  const int tid = threadIdx.x;
  const int n0 = blockIdx.x * 32;
  const int remn = NN - n0;
  const int cnt = remn < 32 ? remn : 32;
  const int n = tid >> 4;
  const int q = tid & 15;

  if (n < cnt) {
    const int node = n0 + n;
    if (q < 2)
      *(f16x8*)&sA[n * 168 + q * 8] = *(const f16x8*)&X1P[node * 16 + q * 8];
    else if (q < 4)
      *(f16x8*)&sA[n * 168 + 144 + (q - 2) * 8] = (f16x8){};
    *(f16x8*)&sA[n * 168 + 16 + q * 8] =
        *(const f16x8*)&X2H[(size_t)node * 128 + q * 8];
  }
  __syncthreads();

  mfma_gemm<32, 512, 160, 168, 8, 1, true, true>(sA, WT + OFF_N1, BF,
      [&](int row, int col, float v) { sH[row * 520 + col] = (h16)v; });
  mfma_gemm<32, 128, 256, 520, 8, 1, false, false, 32, 256>(sH, WT + OFF_N2, BF + 512,
      [&](int row, int col, float v) {
        if (row < cnt) XH[(size_t)(n0 + row) * 128 + col] = (h16)v;
      });
}

// ---------------------------------------------------------------------------
// K2: FUSED edge features + e-MLP + msg GEMM + in-block segment reduce.
// R23 measured-best shape: 64 sorted edges/block, 512 thr, 2 blk/CU.
// ---------------------------------------------------------------------------
__global__ __launch_bounds__(512, 4) void k_edge_mlp(
    const h16* __restrict__ X1P, const h16* __restrict__ X2H,
    const int* __restrict__ ES, const int* __restrict__ ET,
    const h16* __restrict__ XH, const h16* __restrict__ WT,
    const float* __restrict__ be1, const float* __restrict__ be2,
    const float* __restrict__ bmsg,
    h16* __restrict__ EB, float* __restrict__ AGG)
{
  __shared__ __align__(16) h16 sFeat[64 * 568];
  __shared__ int strg[64];
  const int tid = threadIdx.x;
  const long e0 = (long)blockIdx.x * 64;
  const long rem = (long)EE - e0;
  const int cnt = rem < 64 ? (int)rem : 64;
  const int n = tid >> 3;
  const int q = tid & 7;
  h16* Arow = &sFeat[n * 568];
  f16x8 xsv0 = {}, xsv1 = {};

  if (n < cnt) {
    const int s = ES[e0 + n];
    const int t = ET[e0 + n];
    if (q == 0) strg[n] = t;
    float ds = 0.f, ns = 0.f, nt = 0.f;
    if (q < 2) {
      const f16x8 a = *(const f16x8*)&X1P[s * 16 + q * 8];
      const f16x8 b = *(const f16x8*)&X1P[t * 16 + q * 8];
      ds = dot8(a, b, ds); ns = dot8(a, a, ns); nt = dot8(b, b, nt);
      *(f16x8*)&Arow[512 + q * 8] = absdiff8(a, b);
    }
#pragma unroll
    for (int c = 0; c < 2; ++c) {
      const f16x8 a = *(const f16x8*)&X2H[(size_t)s * 128 + q * 16 + c * 8];
      const f16x8 b = *(const f16x8*)&X2H[(size_t)t * 128 + q * 16 + c * 8];
      ds = dot8(a, b, ds); ns = dot8(a, a, ns); nt = dot8(b, b, nt);
      *(f16x8*)&Arow[384 + q * 16 + c * 8] = absdiff8(a, b);
    }
    ds += __shfl_xor(ds, 1); ds += __shfl_xor(ds, 2); ds += __shfl_xor(ds, 4);
    ns += __shfl_xor(ns, 1); ns += __shfl_xor(ns, 2); ns += __shfl_xor(ns, 4);
    nt += __shfl_xor(nt, 1); nt += __shfl_xor(nt, 2); nt += __shfl_xor(nt, 4);
    if (q == 0)
      Arow[528] = (h16)(ds / (fmaxf(sqrtf(ns), EPSC) * fmaxf(sqrtf(nt), EPSC)));

    float ds2 = 0.f, ns2 = 0.f, nt2 = 0.f;
#pragma unroll
    for (int c = 0; c < 2; ++c) {
      const f16x8 a = *(const f16x8*)&XH[(size_t)s * 128 + q * 16 + c * 8];
      const f16x8 b = *(const f16x8*)&XH[(size_t)t * 128 + q * 16 + c * 8];
      if (c == 0) xsv0 = a; else xsv1 = a;
      ds2 = dot8(a, b, ds2); ns2 = dot8(a, a, ns2); nt2 = dot8(b, b, nt2);
      *(f16x8*)&Arow[q * 16 + c * 8]       = a;
      *(f16x8*)&Arow[128 + q * 16 + c * 8] = b;
      *(f16x8*)&Arow[256 + q * 16 + c * 8] = absdiff8(a, b);
    }
    ds2 += __shfl_xor(ds2, 1); ds2 += __shfl_xor(ds2, 2); ds2 += __shfl_xor(ds2, 4);
    ns2 += __shfl_xor(ns2, 1); ns2 += __shfl_xor(ns2, 2); ns2 += __shfl_xor(ns2, 4);
    nt2 += __shfl_xor(nt2, 1); nt2 += __shfl_xor(nt2, 2); nt2 += __shfl_xor(nt2, 4);
    if (q == 0)
      Arow[529] = (h16)(ds2 / (fmaxf(sqrtf(ns2), EPSC) * fmaxf(sqrtf(nt2), EPSC)));
    for (int j = 530 + q; j < 544; j += 8) Arow[j] = (h16)0.f;
  } else {
    if (q == 0) strg[n] = 0;
    for (int j8 = q; j8 < 71; j8 += 8) *(f16x8*)&Arow[j8 * 8] = (f16x8){};
  }
  __syncthreads();

  h16* sHid = sFeat;   // stride 264, overlays features (post-barrier)
  mfma_gemm<64, 256, 544, 568, 8, 1, true, true>(sFeat, WT + OFF_E1, be1,
      [&](int row, int col, float v) { sHid[row * 264 + col] = (h16)v; });
  mfma_gemm<64, 128, 256, 264, 8, 1, false, false>(sHid, WT + OFF_E2, be2,
      [&](int row, int col, float v) {
        const h16 vh = (h16)v;
        if (row < cnt) EB[(size_t)(e0 + row) * 128 + col] = vh;
        sHid[row * 264 + col] = vh;                // e at cols [0,128)
      });
  // park xs beside e at cols [128,256): same post-A-read window as GEMM2 emit
  *(f16x8*)&sFeat[n * 264 + 128 + q * 16]     = xsv0;
  *(f16x8*)&sFeat[n * 264 + 128 + q * 16 + 8] = xsv1;
  __syncthreads();
  // msg GEMM: emit fp32 into the (dead, post-barrier) A region, stride 528B
  mfma_gemm<64, 128, 256, 264, 8, 1, true, true>(sFeat, WT + OFF_MSG, bmsg,
      [&](int row, int col, float v) {
        *(float*)((char*)sFeat + row * 528 + col * 4) = v;
      });
  // segment reduction: sorted trg -> runs; 4 row-groups x 128 cols
  {
    const int c = tid & 127;
    const int g = tid >> 7;
    const int r0 = g * 16;
    if (r0 < cnt) {
      const int rend = (r0 + 16 < cnt) ? r0 + 16 : cnt;
      float acc = 0.f;
      int cur = strg[r0];
      for (int r = r0; r < rend; ++r) {
        const int t = strg[r];
        if (t != cur) {
          atomicAdd(&AGG[(size_t)cur * 128 + c], acc);
          acc = 0.f; cur = t;
        }
        acc += *(const float*)((const char*)sFeat + r * 528 + c * 4);
      }
      atomicAdd(&AGG[(size_t)cur * 128 + c], acc);
    }
  }
}

// ---------------------------------------------------------------------------
// K3: xn = relu([x|agg] @ Wnode + b). 64 nodes/block.
// ---------------------------------------------------------------------------
__global__ __launch_bounds__(256, 4) void k_node_update(
    const h16* __restrict__ XH, const float* __restrict__ AGG,
    const h16* __restrict__ WT, const float* __restrict__ bnode,
    h16* __restrict__ XNH)
{
  __shared__ __align__(16) h16 sA[64 * 264];
  const int tid = threadIdx.x;
  const int n0 = blockIdx.x * 64;
  const int remn = NN - n0;
  const int cnt = remn < 64 ? remn : 64;
  const int n = tid >> 2;
  const int q = tid & 3;

  if (n < cnt) {
    const f16x8* xr = (const f16x8*)&XH[(size_t)(n0 + n) * 128];
    const float4* ar = (const float4*)&AGG[(size_t)(n0 + n) * 128];
    for (int j8 = q; j8 < 16; j8 += 4)
      *(f16x8*)&sA[n * 264 + j8 * 8] = xr[j8];
    for (int j4 = q; j4 < 32; j4 += 4) {
      const float4 b = ar[j4];
      h16* p1 = &sA[n * 264 + 128 + j4 * 4];
      p1[0] = (h16)b.x; p1[1] = (h16)b.y; p1[2] = (h16)b.z; p1[3] = (h16)b.w;
    }
  } else {
    for (int j = q; j < 256; j += 4) sA[n * 264 + j] = (h16)0.f;
  }
  __syncthreads();

  mfma_gemm<64, 128, 256, 264, 4, 1, true, false>(sA, WT + OFF_NODE, bnode,
      [&](int row, int col, float v) {
        if (row < cnt) XNH[(size_t)(n0 + row) * 128 + col] = (h16)v;
      });
}

// ---------------------------------------------------------------------------
// K4: e_mp MLP + classifier. 128 sorted edges/block, 1024 thr; MP1 split into
// 2 K-phases over one [128][264] A buffer (LDS 67.6KB -> target 2 blk/CU).
// Phase1 A = [xn_s|xn_t] (K=256, MP1A); stage2 overwrites cols [0,128) with e
// (EB, coalesced); phase2 K=128 (MP1B). H2 overlays A post-barrier; e_mp
// stride 136 over dead H2; HC fp32 at byte 0 over dead e_mp. Grid 3907.
// ---------------------------------------------------------------------------
__global__ __launch_bounds__(1024, 8) void k_empl(
    const int* __restrict__ ES, const int* __restrict__ ET,
    const int* __restrict__ OID, const h16* __restrict__ XNH,
    const h16* __restrict__ EB, const h16* __restrict__ WT,
    const float* __restrict__ bmp1, const float* __restrict__ bmp2,
    const float* __restrict__ bc1,
    const float* __restrict__ Wc2, const float* __restrict__ bc2,
    float* __restrict__ out)
{
  __shared__ __align__(16) h16 sF[128 * 264];
  const int tid = threadIdx.x;
  const long e0 = (long)blockIdx.x * 128;
  const long rem = (long)EE - e0;
  const int cnt = rem < 128 ? (int)rem : 128;
  const int n = tid >> 3;
  const int q = tid & 7;

  if (n < cnt) {
    const int s = ES[e0 + n];
    const int t = ET[e0 + n];
    const f16x8* xsr = (const f16x8*)&XNH[(size_t)s * 128];
    const f16x8* xtr = (const f16x8*)&XNH[(size_t)t * 128];
    *(f16x8*)&sF[n * 264 + q * 16]           = xsr[q * 2];
    *(f16x8*)&sF[n * 264 + q * 16 + 8]       = xsr[q * 2 + 1];
    *(f16x8*)&sF[n * 264 + 128 + q * 16]     = xtr[q * 2];
    *(f16x8*)&sF[n * 264 + 128 + q * 16 + 8] = xtr[q * 2 + 1];
  } else {
    *(f16x8*)&sF[n * 264 + q * 16]           = (f16x8){};
    *(f16x8*)&sF[n * 264 + q * 16 + 8]       = (f16x8){};
    *(f16x8*)&sF[n * 264 + 128 + q * 16]     = (f16x8){};
    *(f16x8*)&sF[n * 264 + 128 + q * 16 + 8] = (f16x8){};
  }
  __syncthreads();

  h16*  sE  = sF;                       // stride 136 (over dead H2)
  float* sHC = (float*)sF;              // stride 65 fp32 (over dead e_mp)
  mfma_gemm_2p<128, 256, 256, 128, 264, 16, true>(sF,
      WT + OFF_MP1, WT + OFF_MP1B, bmp1,
      [&]() {                            // stage2: e -> cols [0,128)
        if (n < cnt) {
          const f16x8* ebr = (const f16x8*)&EB[(size_t)(e0 + n) * 128];
          *(f16x8*)&sF[n * 264 + q * 16]     = ebr[q * 2];
          *(f16x8*)&sF[n * 264 + q * 16 + 8] = ebr[q * 2 + 1];
        } else {
          *(f16x8*)&sF[n * 264 + q * 16]     = (f16x8){};
          *(f16x8*)&sF[n * 264 + q * 16 + 8] = (f16x8){};
        }
      },
      [&](int row, int col, float v) { sF[row * 264 + col] = (h16)v; });
  mfma_gemm<128, 128, 256, 264, 16, 1, false, true>(sF, WT + OFF_MP2, bmp2,
      [&](int row, int col, float v) { sE[row * 136 + col] = (h16)v; });
  mfma_gemm<128, 64, 128, 136, 16, 1, true, true>(sE, WT + OFF_C1, bc1,
      [&](int row, int col, float v) { sHC[row * 65 + col] = v; });
  if (tid < cnt) {
    float acc = bc2[0];
    for (int k = 0; k < 64; ++k) acc += sHC[tid * 65 + k] * Wc2[k];
    out[OID[e0 + tid]] = acc;
  }
}

// ---------------------------------------------------------------------------
extern "C" void kernel_launch(void* const* d_in, const int* in_sizes, int n_in,
                              void* d_out, int out_size, void* d_ws, size_t ws_size,
                              hipStream_t stream)
{
  const float* x1  = (const float*)d_in[0];
  const float* x2  = (const float*)d_in[1];
  const int*   ei  = (const int*)d_in[2];
  const float* Wh1 = (const float*)d_in[3],  *bh1 = (const float*)d_in[4];
  const float* Wh2 = (const float*)d_in[5],  *bh2 = (const float*)d_in[6];
  const float* Wl1 = (const float*)d_in[7],  *bl1 = (const float*)d_in[8];
  const float* Wl2 = (const float*)d_in[9],  *bl2 = (const float*)d_in[10];
  const float* We1 = (const float*)d_in[11], *be1 = (const float*)d_in[12];
  const float* We2 = (const float*)d_in[13], *be2 = (const float*)d_in[14];
  const float* Wmsg = (const float*)d_in[15], *bmsg = (const float*)d_in[16];
  const float* Wnode = (const float*)d_in[17], *bnode = (const float*)d_in[18];
  const float* Wmp1 = (const float*)d_in[19], *bmp1 = (const float*)d_in[20];
  const float* Wmp2 = (const float*)d_in[21], *bmp2 = (const float*)d_in[22];
  const float* Wc1 = (const float*)d_in[23], *bc1 = (const float*)d_in[24];
  const float* Wc2 = (const float*)d_in[25], *bc2 = (const float*)d_in[26];
  float* out = (float*)d_out;

  // ws layout (~201MB): AGG|EB|WT|XH|XNH|X1P|X2H|BF|CNT|POS|TEX|ES|ET|OID|BS
  float* AGG = (float*)d_ws;
  h16*   EB  = (h16*)(AGG + (size_t)NN * 128);
  h16*   WT  = EB + (size_t)EE * 128;
  h16*   XH  = WT + WT_TOTAL;
  h16*   XNH = XH + (size_t)NN * 128;
  h16*   X1P = XNH + (size_t)NN * 128;
  h16*   X2H = X1P + (size_t)NN * 16;
  float* BF  = (float*)(X2H + (size_t)NN * 128);
  int*   CNT = (int*)(BF + BF_TOTAL);
  int*   POS = CNT + NN;
  int*   TEX = POS + NN;
  int*   ES  = TEX + NN;
  int*   ET  = ES + EE;
  int*   OID = ET + EE;
  int*   BS  = OID + EE;

  k_prep<<<(WT_TOTAL + BF_TOTAL + 255) / 256, 256, 0, stream>>>(
      We1, We2, Wmsg, Wnode, Wmp1, Wmp2, Wc1,
      Wh1, Wl1, Wh2, Wl2, bh1, bl1, bh2, bl2, WT, BF, CNT);
  k_cvt<<<(NN * 16 + NN * 128 + 255) / 256, 256, 0, stream>>>(
      x1, x2, ei, X1P, X2H, CNT, AGG);
  k_scanA<<<SCAN_B, 256, 0, stream>>>(CNT, TEX, BS);
  k_scatter<<<(EE + 255) / 256, 256, 0, stream>>>(ei, TEX, BS, POS, ES, ET, OID);
  k_nenc<<<(NN + 31) / 32, 512, 0, stream>>>(X1P, X2H, WT, BF, XH);
  k_edge_mlp<<<7813, 512, 0, stream>>>(X1P, X2H, ES, ET, XH, WT,
                                       be1, be2, bmsg, EB, AGG);
  k_node_update<<<782, 256, 0, stream>>>(XH, AGG, WT, bnode, XNH);
  k_empl<<<3907, 1024, 0, stream>>>(ES, ET, OID, XNH, EB, WT, bmp1, bmp2, bc1,
                                    Wc2, bc2, out);
}

// Round 14
// 794.599 us; speedup vs baseline: 1.2862x; 1.0059x over previous
//
#include <hip/hip_runtime.h>
#include <hip/hip_bf16.h>
#include <hip/hip_fp16.h>

// CellTrack GNN, MI355X — R27: fp16-mirror conversion fused into k_nenc.
// R26 (799us best, prediction matched): k_empl 2-phase MP1 + fusions banked
// 44us. Remaining cheap slope: k_cvt ran 25313 blocks mostly for conversion;
// k_nenc already visits every node. R27: k_nenc loads x1/x2 fp32, converts
// in-register into its LDS staging AND writes the X1P/X2H mirrors (one fewer
// full pass); k_cvt -> k_hista (grid 1954: trg histogram + grid-stride AGG
// zero). Math identical everywhere.
// ws: AGG|EB|WT|XH|XNH|X1P|X2H|BF|CNT|POS|TEX|ES|ET|OID|BS ~201MB.

using fp16 = __half;
typedef _Float16 h16;
typedef _Float16 f16x8 __attribute__((ext_vector_type(8)));
typedef _Float16 h16x2 __attribute__((ext_vector_type(2)));
typedef short s16x8 __attribute__((ext_vector_type(8)));
typedef float f32x4 __attribute__((ext_vector_type(4)));

#define NN 50000
#define EE 500000
#define EPSC 1e-8f
#define SCAN_B 196   // ceil(NN/256)

__device__ __forceinline__ float reluf(float v){ return v > 0.f ? v : 0.f; }

__device__ __forceinline__ float dot8(const f16x8 a, const f16x8 b, float acc)
{
#pragma unroll
  for (int i = 0; i < 4; ++i) {
    const h16x2 av = {a[2 * i], a[2 * i + 1]};
    const h16x2 bv = {b[2 * i], b[2 * i + 1]};
    acc = __builtin_amdgcn_fdot2(av, bv, acc, false);
  }
  return acc;
}

__device__ __forceinline__ f16x8 absdiff8(const f16x8 a, const f16x8 b)
{
  const f16x8 d = a - b;
  s16x8 di = __builtin_bit_cast(s16x8, d);
  di &= (short)0x7fff;
  return __builtin_bit_cast(f16x8, di);
}

// WT sub-buffer offsets (halves)
#define OFF_E1   0         // [256][544]  (527 real, permuted col order)
#define OFF_E2   139264    // [128][256]
#define OFF_MSG  172032    // [128][256]  ([e|xs] order)
#define OFF_NODE 204800    // [128][256]
#define OFF_MP1  237568    // MP1A [256][256]  (k over [xn_s|xn_t])
#define OFF_MP1B 303104    // MP1B [256][128]  (k over e)
#define OFF_MP2  335872    // [128][256]
#define OFF_C1   368640    // [64][128]
#define OFF_N1   376832    // [512][160]  block-diag [Wh1 | Wl1]
#define OFF_N2   458752    // [128][256]  packed block-diag (R25)
#define N2_END   491520
#define WT_TOTAL 524288
#define BF_TOTAL 640

// ---------------------------------------------------------------------------
// k_prep: fp32 weights -> fp16 transposed; also zeroes CNT+POS (2*NN ints).
// ---------------------------------------------------------------------------
__global__ __launch_bounds__(256) void k_prep(
    const float* __restrict__ We1, const float* __restrict__ We2,
    const float* __restrict__ Wmsg, const float* __restrict__ Wnode,
    const float* __restrict__ Wmp1, const float* __restrict__ Wmp2,
    const float* __restrict__ Wc1,
    const float* __restrict__ Wh1, const float* __restrict__ Wl1,
    const float* __restrict__ Wh2, const float* __restrict__ Wl2,
    const float* __restrict__ bh1, const float* __restrict__ bl1,
    const float* __restrict__ bh2, const float* __restrict__ bl2,
    h16* __restrict__ WT, float* __restrict__ BF, int* __restrict__ CNT)
{
  int idx = blockIdx.x * 256 + threadIdx.x;
  if (idx < 2 * NN) CNT[idx] = 0;           // CNT + POS (contiguous)
  if (idx >= WT_TOTAL) {
    const int b = idx - WT_TOTAL;
    if (b < 512) BF[b] = (b < 256) ? bh1[b] : bl1[b - 256];
    else if (b < BF_TOTAL) {
      const int c = b - 512;
      BF[b] = (c < 32) ? bh2[c] : bl2[c - 32];
    }
    return;
  }
  h16 v;
  if (idx < OFF_E2) {
    const int L = idx, n = L / 544, k = L % 544;
    int r;
    if      (k < 128) r = 142 + k;
    else if (k < 256) r = 270 + (k - 128);
    else if (k < 384) r = 398 + (k - 256);
    else if (k < 512) r = 13 + (k - 384);
    else if (k < 525) r = k - 512;
    else if (k == 528) r = 141;
    else if (k == 529) r = 526;
    else r = -1;
    v = (h16)((r >= 0) ? We1[r * 256 + n] : 0.f);
  } else if (idx < OFF_MSG) {
    const int L = idx - OFF_E2, n = L >> 8, k = L & 255;
    v = (h16)We2[k * 128 + n];
  } else if (idx < OFF_NODE) {
    const int L = idx - OFF_MSG, n = L >> 8, k = L & 255;
    const int ko = (k < 128) ? (128 + k) : (k - 128);   // [e|xs] order
    v = (h16)Wmsg[ko * 128 + n];
  } else if (idx < OFF_MP1) {
    const int L = idx - OFF_NODE, n = L >> 8, k = L & 255;
    v = (h16)Wnode[k * 128 + n];
  } else if (idx < OFF_MP1B) {              // MP1A [256][256]: k over xn_s|xn_t
    const int L = idx - OFF_MP1, n = L >> 8, k = L & 255;
    v = (h16)Wmp1[k * 256 + n];
  } else if (idx < OFF_MP2) {               // MP1B [256][128]: k over e
    const int L = idx - OFF_MP1B, n = L >> 7, k = L & 127;
    v = (h16)Wmp1[(256 + k) * 256 + n];
  } else if (idx < OFF_C1) {
    const int L = idx - OFF_MP2, n = L >> 8, k = L & 255;
    v = (h16)Wmp2[k * 128 + n];
  } else if (idx < OFF_N1) {
    const int L = idx - OFF_C1, n = L >> 7, k = L & 127;
    v = (h16)Wc1[k * 64 + n];
  } else if (idx < OFF_N2) {
    const int L = idx - OFF_N1, n = L / 160, k = L % 160;
    float f = 0.f;
    if (n < 256) { if (k < 13) f = Wh1[k * 256 + n]; }
    else { if (k >= 16 && k < 144) f = Wl1[(k - 16) * 256 + (n - 256)]; }
    v = (h16)f;
  } else if (idx < N2_END) {
    const int L = idx - OFF_N2, n = L >> 8, k = L & 255;
    v = (h16)((n < 32) ? Wh2[k * 32 + n] : Wl2[k * 96 + (n - 32)]);
  } else {
    v = (h16)0.f;
  }
  WT[idx] = v;
}

// k_hista: trg histogram + grid-stride AGG zero. Grid ceil(EE/256).
__global__ __launch_bounds__(256) void k_hista(
    const int* __restrict__ ei, int* __restrict__ CNT, float* __restrict__ AGG)
{
  const int idx = blockIdx.x * 256 + threadIdx.x;
  if (idx < EE) atomicAdd(&CNT[ei[EE + idx]], 1);
  float4* a4 = (float4*)AGG;
  const int tot4 = NN * 32;                 // NN*128 floats / 4
  const int stride = gridDim.x * 256;
  for (int i = idx; i < tot4; i += stride)
    a4[i] = (float4){0.f, 0.f, 0.f, 0.f};
}

// --------------------------- hierarchical scan -----------------------------
__global__ __launch_bounds__(256) void k_scanA(
    const int* __restrict__ CNT, int* __restrict__ TEX, int* __restrict__ BS)
{
  __shared__ int sd[256];
  const int tid = threadIdx.x;
  const int i = blockIdx.x * 256 + tid;
  const int v = (i < NN) ? CNT[i] : 0;
  sd[tid] = v;
  __syncthreads();
  for (int off = 1; off < 256; off <<= 1) {
    const int x = (tid >= off) ? sd[tid - off] : 0;
    __syncthreads();
    sd[tid] += x;
    __syncthreads();
  }
  if (i < NN) TEX[i] = sd[tid] - v;
  if (tid == 255) BS[blockIdx.x] = sd[255];
}

// k_scatter: per-block exclusive scan of BS (196 entries) in LDS, then scatter.
__global__ __launch_bounds__(256) void k_scatter(
    const int* __restrict__ ei, const int* __restrict__ TEX,
    const int* __restrict__ BS, int* __restrict__ POS,
    int* __restrict__ ES, int* __restrict__ ET, int* __restrict__ OID)
{
  __shared__ int sbase[256];
  const int tid = threadIdx.x;
  const int v = (tid < SCAN_B) ? BS[tid] : 0;
  sbase[tid] = v;
  __syncthreads();
  for (int off = 1; off < 256; off <<= 1) {
    const int x = (tid >= off) ? sbase[tid - off] : 0;
    __syncthreads();
    sbase[tid] += x;
    __syncthreads();
  }
  const int excl = sbase[tid] - v;
  __syncthreads();
  sbase[tid] = excl;
  __syncthreads();

  const int e = blockIdx.x * 256 + tid;
  if (e >= EE) return;
  const int t = ei[EE + e];
  const int p = atomicAdd(&POS[t], 1);
  const int idx = sbase[t >> 8] + TEX[t] + p;
  ES[idx] = ei[e];
  ET[idx] = t;
  OID[idx] = e;
}

// ---------------------------------------------------------------------------
// chunked B-prefetch GEMM phase: accumulates into acc (shared across phases).
// ---------------------------------------------------------------------------
template<int RT, int NT, int KP, int LDA, int CHUNK>
__device__ __forceinline__ void gemm_phase(const h16* sA, const h16* wbase,
    f32x4 (&acc)[RT][NT], int m, int quad)
{
  constexpr int NSTEPS = KP / 32;
  constexpr int NCH = (NSTEPS + CHUNK - 1) / CHUNK;
  f16x8 breg[2][CHUNK][NT];
#pragma unroll
  for (int s = 0; s < CHUNK; ++s)
    if (s < NSTEPS)
#pragma unroll
      for (int j = 0; j < NT; ++j)
        breg[0][s][j] = *(const f16x8*)&wbase[(size_t)j * 16 * KP + s * 32];
  asm volatile("" ::: "memory");
#pragma unroll
  for (int c = 0; c < NCH; ++c) {
    if (c + 1 < NCH) {
#pragma unroll
      for (int s = 0; s < CHUNK; ++s) {
        const int st = (c + 1) * CHUNK + s;
        if (st < NSTEPS)
#pragma unroll
          for (int j = 0; j < NT; ++j)
            breg[(c + 1) & 1][s][j] =
                *(const f16x8*)&wbase[(size_t)j * 16 * KP + st * 32];
      }
    }
#pragma unroll
    for (int s = 0; s < CHUNK; ++s) {
      const int st = c * CHUNK + s;
      if (st < NSTEPS) {
        const int k0 = st * 32;
#pragma unroll
        for (int r = 0; r < RT; ++r) {
          const f16x8 af = *(const f16x8*)&sA[(r * 16 + m) * LDA + k0 + quad * 8];
#pragma unroll
          for (int j = 0; j < NT; ++j)
            acc[r][j] = __builtin_amdgcn_mfma_f32_16x16x32_f16(af, breg[c & 1][s][j], acc[r][j], 0, 0, 0);
        }
      }
    }
    asm volatile("" ::: "memory");
  }
}

// ---------------------------------------------------------------------------
// MFMA GEMM: C[ROWS][UDIM] = act(A[ROWS][KP] @ WT^T + b).
// ---------------------------------------------------------------------------
template<int ROWS, int UDIM, int KP, int LDA, int WAVES, int RS, bool RELU,
         bool ENDSYNC, int ACOLS = 0, int AOFF = 0, typename F>
__device__ __forceinline__ void mfma_gemm(const h16* sA,
    const h16* __restrict__ WT, const float* __restrict__ bias, F emit)
{
  constexpr int CS = WAVES / RS;
  constexpr int RG = ROWS / RS;
  constexpr int RT = RG / 16;
  constexpr int NPW0 = UDIM / CS;
  constexpr int NPW = (NPW0 < 16) ? 16 : NPW0;
  constexpr int NT = NPW / 16;
  constexpr int NSTEPS = KP / 32;
  constexpr int CH0 = (NT >= 8) ? 1 : ((NT >= 4) ? 2 : 4);
  constexpr int CHUNK = (NSTEPS < CH0) ? NSTEPS : CH0;
  const int tid = threadIdx.x;
  const int wave = tid >> 6;
  const int lane = tid & 63;
  const int m = lane & 15;
  const int quad = lane >> 4;
  const int wr = wave % RS;
  const int wc = wave / RS;
  const int rbase = wr * RG;
  const int n0 = wc * NPW;
  const bool active = (n0 < UDIM);
  const int aoff = (ACOLS > 0 && n0 >= ACOLS) ? AOFF : 0;

  f32x4 acc[RT][NT];
#pragma unroll
  for (int r = 0; r < RT; ++r)
#pragma unroll
    for (int j = 0; j < NT; ++j) acc[r][j] = (f32x4){0.f, 0.f, 0.f, 0.f};
  float bb[NT];

  if (active) {
    const h16* wbase = &WT[(size_t)(n0 + m) * KP + quad * 8];
#pragma unroll
    for (int j = 0; j < NT; ++j) bb[j] = bias[n0 + j * 16 + m];
    gemm_phase<RT, NT, KP, LDA, CHUNK>(&sA[rbase * LDA + aoff], wbase, acc, m, quad);
  }
  __syncthreads();
  if (active) {
#pragma unroll
    for (int j = 0; j < NT; ++j) {
      const int col = n0 + j * 16 + m;
#pragma unroll
      for (int r = 0; r < RT; ++r)
#pragma unroll
        for (int g = 0; g < 4; ++g) {
          const int row = rbase + r * 16 + quad * 4 + g;
          float v = acc[r][j][g] + bb[j];
          if (RELU) v = reluf(v);
          emit(row, col, v);
        }
    }
  }
  if (ENDSYNC) __syncthreads();
}

// ---------------------------------------------------------------------------
// two-phase GEMM: acc over KP1 (WT1) then stage2() refills A cols and acc
// over KP2 (WT2); single bias+emit. Used by k_empl's MP1 split.
// ---------------------------------------------------------------------------
template<int ROWS, int UDIM, int KP1, int KP2, int LDA, int WAVES, bool RELU,
         typename S, typename F>
__device__ __forceinline__ void mfma_gemm_2p(const h16* sA,
    const h16* __restrict__ WT1, const h16* __restrict__ WT2,
    const float* __restrict__ bias, S stage2, F emit)
{
  constexpr int RT = ROWS / 16;
  constexpr int NPW0 = UDIM / WAVES;
  constexpr int NPW = (NPW0 < 16) ? 16 : NPW0;
  constexpr int NT = NPW / 16;
  const int tid = threadIdx.x;
  const int wave = tid >> 6;
  const int lane = tid & 63;
  const int m = lane & 15;
  const int quad = lane >> 4;
  const int n0 = wave * NPW;
  const bool active = (n0 < UDIM);

  f32x4 acc[RT][NT];
#pragma unroll
  for (int r = 0; r < RT; ++r)
#pragma unroll
    for (int j = 0; j < NT; ++j) acc[r][j] = (f32x4){0.f, 0.f, 0.f, 0.f};
  float bb[NT];

  if (active) {
#pragma unroll
    for (int j = 0; j < NT; ++j) bb[j] = bias[n0 + j * 16 + m];
    gemm_phase<RT, NT, KP1, LDA, 2>(sA,
        &WT1[(size_t)(n0 + m) * KP1 + quad * 8], acc, m, quad);
  }
  __syncthreads();          // all phase-1 A reads done
  stage2();                 // overwrite A cols [0,KP2) with phase-2 operand
  __syncthreads();
  if (active) {
    gemm_phase<RT, NT, KP2, LDA, 2>(sA,
        &WT2[(size_t)(n0 + m) * KP2 + quad * 8], acc, m, quad);
  }
  __syncthreads();          // all phase-2 A reads done -> emits may overlay
  if (active) {
#pragma unroll
    for (int j = 0; j < NT; ++j) {
      const int col = n0 + j * 16 + m;
#pragma unroll
      for (int r = 0; r < RT; ++r)
#pragma unroll
        for (int g = 0; g < 4; ++g) {
          const int row = r * 16 + quad * 4 + g;
          float v = acc[r][j][g] + bb[j];
          if (RELU) v = reluf(v);
          emit(row, col, v);
        }
    }
  }
  __syncthreads();
}

// ---------------------------------------------------------------------------
// K0: node encoder via MFMA + fp16-mirror production (fused conversion).
// 32 nodes/block, 512 thr (grid 1563, last 16). Loads x1/x2 fp32, converts
// in-register -> sA staging AND X1P/X2H mirrors.
// ---------------------------------------------------------------------------
__global__ __launch_bounds__(512, 4) void k_nenc(
    const float* __restrict__ x1, const float* __restrict__ x2,
    const h16* __restrict__ WT, const float* __restrict__ BF,
    h16* __restrict__ XH, h16* __restrict__ X1P, h16* __restrict__ X2H)
{
  __shared__ __align__(16) h16 sA[32 * 168];
  __shared__ __align__(16) h16 sH[32 * 520];
  const int tid = threadIdx.x;
  const int n0 = blockIdx.x * 32;
  const int remn = NN - n0;
  const int cnt = remn < 32 ? remn : 32;
  const int n = tid >> 4;
  const int q = tid & 15;

  if (n < cnt) {
    const int node = n0 + n;
    // x1: 13 real + 3 pad -> sA cols [0,16) and X1P row
    const h16 v1 = (h16)((q < 13) ? x1[node * 13 + q] : 0.f);
    sA[n * 168 + q] = v1;
    X1P[node * 16 + q] = v1;
    // x2: 8 floats per thread -> f16x8 -> sA cols [16,144) and X2H row
    const float4* x2f4 = (const float4*)&x2[(size_t)node * 128 + q * 8];
    const float4 a = x2f4[0], b = x2f4[1];
    f16x8 h;
    h[0] = (h16)a.x; h[1] = (h16)a.y; h[2] = (h16)a.z; h[3] = (h16)a.w;
    h[4] = (h16)b.x; h[5] = (h16)b.y; h[6] = (h16)b.z; h[7] = (h16)b.w;
    *(f16x8*)&sA[n * 168 + 16 + q * 8] = h;
    *(f16x8*)&X2H[(size_t)node * 128 + q * 8] = h;
    // trailing zero pad cols [144,160)
    if (q < 2) *(f16x8*)&sA[n * 168 + 144 + q * 8] = (f16x8){};
  }
  __syncthreads();

  mfma_gemm<32, 512, 160, 168, 8, 1, true, true>(sA, WT + OFF_N1, BF,
      [&](int row, int col, float v) { sH[row * 520 + col] = (h16)v; });
  mfma_gemm<32, 128, 256, 520, 8, 1, false, false, 32, 256>(sH, WT + OFF_N2, BF + 512,
      [&](int row, int col, float v) {
        if (row < cnt) XH[(size_t)(n0 + row) * 128 + col] = (h16)v;
      });
}

// ---------------------------------------------------------------------------
// K2: FUSED edge features + e-MLP + msg GEMM + in-block segment reduce.
// R23 measured-best shape: 64 sorted edges/block, 512 thr, 2 blk/CU.
// ---------------------------------------------------------------------------
__global__ __launch_bounds__(512, 4) void k_edge_mlp(
    const h16* __restrict__ X1P, const h16* __restrict__ X2H,
    const int* __restrict__ ES, const int* __restrict__ ET,
    const h16* __restrict__ XH, const h16* __restrict__ WT,
    const float* __restrict__ be1, const float* __restrict__ be2,
    const float* __restrict__ bmsg,
    h16* __restrict__ EB, float* __restrict__ AGG)
{
  __shared__ __align__(16) h16 sFeat[64 * 568];
  __shared__ int strg[64];
  const int tid = threadIdx.x;
  const long e0 = (long)blockIdx.x * 64;
  const long rem = (long)EE - e0;
  const int cnt = rem < 64 ? (int)rem : 64;
  const int n = tid >> 3;
  const int q = tid & 7;
  h16* Arow = &sFeat[n * 568];
  f16x8 xsv0 = {}, xsv1 = {};

  if (n < cnt) {
    const int s = ES[e0 + n];
    const int t = ET[e0 + n];
    if (q == 0) strg[n] = t;
    float ds = 0.f, ns = 0.f, nt = 0.f;
    if (q < 2) {
      const f16x8 a = *(const f16x8*)&X1P[s * 16 + q * 8];
      const f16x8 b = *(const f16x8*)&X1P[t * 16 + q * 8];
      ds = dot8(a, b, ds); ns = dot8(a, a, ns); nt = dot8(b, b, nt);
      *(f16x8*)&Arow[512 + q * 8] = absdiff8(a, b);
    }
#pragma unroll
    for (int c = 0; c < 2; ++c) {
      const f16x8 a = *(const f16x8*)&X2H[(size_t)s * 128 + q * 16 + c * 8];
      const f16x8 b = *(const f16x8*)&X2H[(size_t)t * 128 + q * 16 + c * 8];
      ds = dot8(a, b, ds); ns = dot8(a, a, ns); nt = dot8(b, b, nt);
      *(f16x8*)&Arow[384 + q * 16 + c * 8] = absdiff8(a, b);
    }
    ds += __shfl_xor(ds, 1); ds += __shfl_xor(ds, 2); ds += __shfl_xor(ds, 4);
    ns += __shfl_xor(ns, 1); ns += __shfl_xor(ns, 2); ns += __shfl_xor(ns, 4);
    nt += __shfl_xor(nt, 1); nt += __shfl_xor(nt, 2); nt += __shfl_xor(nt, 4);
    if (q == 0)
      Arow[528] = (h16)(ds / (fmaxf(sqrtf(ns), EPSC) * fmaxf(sqrtf(nt), EPSC)));

    float ds2 = 0.f, ns2 = 0.f, nt2 = 0.f;
#pragma unroll
    for (int c = 0; c < 2; ++c) {
      const f16x8 a = *(const f16x8*)&XH[(size_t)s * 128 + q * 16 + c * 8];
      const f16x8 b = *(const f16x8*)&XH[(size_t)t * 128 + q * 16 + c * 8];
      if (c == 0) xsv0 = a; else xsv1 = a;
      ds2 = dot8(a, b, ds2); ns2 = dot8(a, a, ns2); nt2 = dot8(b, b, nt2);
      *(f16x8*)&Arow[q * 16 + c * 8]       = a;
      *(f16x8*)&Arow[128 + q * 16 + c * 8] = b;
      *(f16x8*)&Arow[256 + q * 16 + c * 8] = absdiff8(a, b);
    }
    ds2 += __shfl_xor(ds2, 1); ds2 += __shfl_xor(ds2, 2); ds2 += __shfl_xor(ds2, 4);
    ns2 += __shfl_xor(ns2, 1); ns2 += __shfl_xor(ns2, 2); ns2 += __shfl_xor(ns2, 4);
    nt2 += __shfl_xor(nt2, 1); nt2 += __shfl_xor(nt2, 2); nt2 += __shfl_xor(nt2, 4);
    if (q == 0)
      Arow[529] = (h16)(ds2 / (fmaxf(sqrtf(ns2), EPSC) * fmaxf(sqrtf(nt2), EPSC)));
    for (int j = 530 + q; j < 544; j += 8) Arow[j] = (h16)0.f;
  } else {
    if (q == 0) strg[n] = 0;
    for (int j8 = q; j8 < 71; j8 += 8) *(f16x8*)&Arow[j8 * 8] = (f16x8){};
  }
  __syncthreads();

  h16* sHid = sFeat;   // stride 264, overlays features (post-barrier)
  mfma_gemm<64, 256, 544, 568, 8, 1, true, true>(sFeat, WT + OFF_E1, be1,
      [&](int row, int col, float v) { sHid[row * 264 + col] = (h16)v; });
  mfma_gemm<64, 128, 256, 264, 8, 1, false, false>(sHid, WT + OFF_E2, be2,
      [&](int row, int col, float v) {
        const h16 vh = (h16)v;
        if (row < cnt) EB[(size_t)(e0 + row) * 128 + col] = vh;
        sHid[row * 264 + col] = vh;                // e at cols [0,128)
      });
  // park xs beside e at cols [128,256): same post-A-read window as GEMM2 emit
  *(f16x8*)&sFeat[n * 264 + 128 + q * 16]     = xsv0;
  *(f16x8*)&sFeat[n * 264 + 128 + q * 16 + 8] = xsv1;
  __syncthreads();
  // msg GEMM: emit fp32 into the (dead, post-barrier) A region, stride 528B
  mfma_gemm<64, 128, 256, 264, 8, 1, true, true>(sFeat, WT + OFF_MSG, bmsg,
      [&](int row, int col, float v) {
        *(float*)((char*)sFeat + row * 528 + col * 4) = v;
      });
  // segment reduction: sorted trg -> runs; 4 row-groups x 128 cols
  {
    const int c = tid & 127;
    const int g = tid >> 7;
    const int r0 = g * 16;
    if (r0 < cnt) {
      const int rend = (r0 + 16 < cnt) ? r0 + 16 : cnt;
      float acc = 0.f;
      int cur = strg[r0];
      for (int r = r0; r < rend; ++r) {
        const int t = strg[r];
        if (t != cur) {
          atomicAdd(&AGG[(size_t)cur * 128 + c], acc);
          acc = 0.f; cur = t;
        }
        acc += *(const float*)((const char*)sFeat + r * 528 + c * 4);
      }
      atomicAdd(&AGG[(size_t)cur * 128 + c], acc);
    }
  }
}

// ---------------------------------------------------------------------------
// K3: xn = relu([x|agg] @ Wnode + b). 64 nodes/block.
// ---------------------------------------------------------------------------
__global__ __launch_bounds__(256, 4) void k_node_update(
    const h16* __restrict__ XH, const float* __restrict__ AGG,
    const h16* __restrict__ WT, const float* __restrict__ bnode,
    h16* __restrict__ XNH)
{
  __shared__ __align__(16) h16 sA[64 * 264];
  const int tid = threadIdx.x;
  const int n0 = blockIdx.x * 64;
  const int remn = NN - n0;
  const int cnt = remn < 64 ? remn : 64;
  const int n = tid >> 2;
  const int q = tid & 3;

  if (n < cnt) {
    const f16x8* xr = (const f16x8*)&XH[(size_t)(n0 + n) * 128];
    const float4* ar = (const float4*)&AGG[(size_t)(n0 + n) * 128];
    for (int j8 = q; j8 < 16; j8 += 4)
      *(f16x8*)&sA[n * 264 + j8 * 8] = xr[j8];
    for (int j4 = q; j4 < 32; j4 += 4) {
      const float4 b = ar[j4];
      h16* p1 = &sA[n * 264 + 128 + j4 * 4];
      p1[0] = (h16)b.x; p1[1] = (h16)b.y; p1[2] = (h16)b.z; p1[3] = (h16)b.w;
    }
  } else {
    for (int j = q; j < 256; j += 4) sA[n * 264 + j] = (h16)0.f;
  }
  __syncthreads();

  mfma_gemm<64, 128, 256, 264, 4, 1, true, false>(sA, WT + OFF_NODE, bnode,
      [&](int row, int col, float v) {
        if (row < cnt) XNH[(size_t)(n0 + row) * 128 + col] = (h16)v;
      });
}

// ---------------------------------------------------------------------------
// K4: e_mp MLP + classifier. 128 sorted edges/block, 1024 thr; MP1 split into
// 2 K-phases over one [128][264] A buffer (LDS 67.6KB, 2 blk/CU). Grid 3907.
// ---------------------------------------------------------------------------
__global__ __launch_bounds__(1024, 8) void k_empl(
    const int* __restrict__ ES, const int* __restrict__ ET,
    const int* __restrict__ OID, const h16* __restrict__ XNH,
    const h16* __restrict__ EB, const h16* __restrict__ WT,
    const float* __restrict__ bmp1, const float* __restrict__ bmp2,
    const float* __restrict__ bc1,
    const float* __restrict__ Wc2, const float* __restrict__ bc2,
    float* __restrict__ out)
{
  __shared__ __align__(16) h16 sF[128 * 264];
  const int tid = threadIdx.x;
  const long e0 = (long)blockIdx.x * 128;
  const long rem = (long)EE - e0;
  const int cnt = rem < 128 ? (int)rem : 128;
  const int n = tid >> 3;
  const int q = tid & 7;

  if (n < cnt) {
    const int s = ES[e0 + n];
    const int t = ET[e0 + n];
    const f16x8* xsr = (const f16x8*)&XNH[(size_t)s * 128];
    const f16x8* xtr = (const f16x8*)&XNH[(size_t)t * 128];
    *(f16x8*)&sF[n * 264 + q * 16]           = xsr[q * 2];
    *(f16x8*)&sF[n * 264 + q * 16 + 8]       = xsr[q * 2 + 1];
    *(f16x8*)&sF[n * 264 + 128 + q * 16]     = xtr[q * 2];
    *(f16x8*)&sF[n * 264 + 128 + q * 16 + 8] = xtr[q * 2 + 1];
  } else {
    *(f16x8*)&sF[n * 264 + q * 16]           = (f16x8){};
    *(f16x8*)&sF[n * 264 + q * 16 + 8]       = (f16x8){};
    *(f16x8*)&sF[n * 264 + 128 + q * 16]     = (f16x8){};
    *(f16x8*)&sF[n * 264 + 128 + q * 16 + 8] = (f16x8){};
  }
  __syncthreads();

  h16*  sE  = sF;                       // stride 136 (over dead H2)
  float* sHC = (float*)sF;              // stride 65 fp32 (over dead e_mp)
  mfma_gemm_2p<128, 256, 256, 128, 264, 16, true>(sF,
      WT + OFF_MP1, WT + OFF_MP1B, bmp1,
      [&]() {                            // stage2: e -> cols [0,128)
        if (n < cnt) {
          const f16x8* ebr = (const f16x8*)&EB[(size_t)(e0 + n) * 128];
          *(f16x8*)&sF[n * 264 + q * 16]     = ebr[q * 2];
          *(f16x8*)&sF[n * 264 + q * 16 + 8] = ebr[q * 2 + 1];
        } else {
          *(f16x8*)&sF[n * 264 + q * 16]     = (f16x8){};
          *(f16x8*)&sF[n * 264 + q * 16 + 8] = (f16x8){};
        }
      },
      [&](int row, int col, float v) { sF[row * 264 + col] = (h16)v; });
  mfma_gemm<128, 128, 256, 264, 16, 1, false, true>(sF, WT + OFF_MP2, bmp2,
      [&](int row, int col, float v) { sE[row * 136 + col] = (h16)v; });
  mfma_gemm<128, 64, 128, 136, 16, 1, true, true>(sE, WT + OFF_C1, bc1,
      [&](int row, int col, float v) { sHC[row * 65 + col] = v; });
  if (tid < cnt) {
    float acc = bc2[0];
    for (int k = 0; k < 64; ++k) acc += sHC[tid * 65 + k] * Wc2[k];
    out[OID[e0 + tid]] = acc;
  }
}

// ---------------------------------------------------------------------------
extern "C" void kernel_launch(void* const* d_in, const int* in_sizes, int n_in,
                              void* d_out, int out_size, void* d_ws, size_t ws_size,
                              hipStream_t stream)
{
  const float* x1  = (const float*)d_in[0];
  const float* x2  = (const float*)d_in[1];
  const int*   ei  = (const int*)d_in[2];
  const float* Wh1 = (const float*)d_in[3],  *bh1 = (const float*)d_in[4];
  const float* Wh2 = (const float*)d_in[5],  *bh2 = (const float*)d_in[6];
  const float* Wl1 = (const float*)d_in[7],  *bl1 = (const float*)d_in[8];
  const float* Wl2 = (const float*)d_in[9],  *bl2 = (const float*)d_in[10];
  const float* We1 = (const float*)d_in[11], *be1 = (const float*)d_in[12];
  const float* We2 = (const float*)d_in[13], *be2 = (const float*)d_in[14];
  const float* Wmsg = (const float*)d_in[15], *bmsg = (const float*)d_in[16];
  const float* Wnode = (const float*)d_in[17], *bnode = (const float*)d_in[18];
  const float* Wmp1 = (const float*)d_in[19], *bmp1 = (const float*)d_in[20];
  const float* Wmp2 = (const float*)d_in[21], *bmp2 = (const float*)d_in[22];
  const float* Wc1 = (const float*)d_in[23], *bc1 = (const float*)d_in[24];
  const float* Wc2 = (const float*)d_in[25], *bc2 = (const float*)d_in[26];
  float* out = (float*)d_out;

  // ws layout (~201MB): AGG|EB|WT|XH|XNH|X1P|X2H|BF|CNT|POS|TEX|ES|ET|OID|BS
  float* AGG = (float*)d_ws;
  h16*   EB  = (h16*)(AGG + (size_t)NN * 128);
  h16*   WT  = EB + (size_t)EE * 128;
  h16*   XH  = WT + WT_TOTAL;
  h16*   XNH = XH + (size_t)NN * 128;
  h16*   X1P = XNH + (size_t)NN * 128;
  h16*   X2H = X1P + (size_t)NN * 16;
  float* BF  = (float*)(X2H + (size_t)NN * 128);
  int*   CNT = (int*)(BF + BF_TOTAL);
  int*   POS = CNT + NN;
  int*   TEX = POS + NN;
  int*   ES  = TEX + NN;
  int*   ET  = ES + EE;
  int*   OID = ET + EE;
  int*   BS  = OID + EE;

  k_prep<<<(WT_TOTAL + BF_TOTAL + 255) / 256, 256, 0, stream>>>(
      We1, We2, Wmsg, Wnode, Wmp1, Wmp2, Wc1,
      Wh1, Wl1, Wh2, Wl2, bh1, bl1, bh2, bl2, WT, BF, CNT);
  k_hista<<<(EE + 255) / 256, 256, 0, stream>>>(ei, CNT, AGG);
  k_scanA<<<SCAN_B, 256, 0, stream>>>(CNT, TEX, BS);
  k_scatter<<<(EE + 255) / 256, 256, 0, stream>>>(ei, TEX, BS, POS, ES, ET, OID);
  k_nenc<<<(NN + 31) / 32, 512, 0, stream>>>(x1, x2, WT, BF, XH, X1P, X2H);
  k_edge_mlp<<<7813, 512, 0, stream>>>(X1P, X2H, ES, ET, XH, WT,
                                       be1, be2, bmsg, EB, AGG);
  k_node_update<<<782, 256, 0, stream>>>(XH, AGG, WT, bnode, XNH);
  k_empl<<<3907, 1024, 0, stream>>>(ES, ET, OID, XNH, EB, WT, bmp1, bmp2, bc1,
                                    Wc2, bc2, out);
}